// Round 2
// baseline (4817.769 us; speedup 1.0000x reference)
//
#include <hip/hip_runtime.h>
#include <hip/hip_bf16.h>

// Problem constants (MobiusCollapseLayer): B=4,S=2048,D=1024,P=9,M=256, 3 twists
constexpr int Bb = 4, Ss = 2048, Dd = 1024, Pp = 9, Mm = 256;
constexpr int Nn = Bb * Ss;           // 8192 tokens
constexpr int Kcat = Pp * Mm;         // 2304
constexpr float EPSf = 1e-6f;

// ---------------- prep: fold rot into weights ----------------
// dst[pb,r,c] = rotate columns 0,1 of src[pb,r,:] by theta[pb]
__global__ void rotcopy_k(const float* __restrict__ src, float* __restrict__ dst,
                          int R, int C, const float* __restrict__ theta, int Pb)
{
    long total = (long)Pb * R * C;
    long idx = (long)blockIdx.x * 256 + threadIdx.x;
    if (idx >= total) return;
    int c = (int)(idx % C);
    long rp = idx / C;
    int r = (int)(rp % R);
    int pb = (int)(rp / R);
    float th = theta[pb];
    const float* s = src + ((long)pb * R + r) * C;
    float v;
    if (c == 0)      v = s[0] * cosf(th) - s[1] * sinf(th);
    else if (c == 1) v = s[0] * sinf(th) + s[1] * cosf(th);
    else             v = s[c];
    dst[idx] = v;
}

// Wa (P,D,M) -> Wac (D, P*M) with per-p rotation of m-columns 0,1
__global__ void wacat_k(const float* __restrict__ Wa, const float* __restrict__ tha,
                        float* __restrict__ dst)
{
    int idx = blockIdx.x * 256 + threadIdx.x;
    if (idx >= Pp * Dd * Mm) return;
    int m = idx & (Mm - 1);
    int rest = idx >> 8;          // /M
    int d = rest & (Dd - 1);
    int p = rest >> 10;           // /D
    const float* s = Wa + ((long)p * Dd + d) * Mm;
    float th = tha[p];
    float v;
    if (m == 0)      v = s[0] * cosf(th) - s[1] * sinf(th);
    else if (m == 1) v = s[0] * sinf(th) + s[1] * cosf(th);
    else             v = s[m];
    dst[(long)d * Kcat + p * Mm + m] = v;
}

// ---------------- neighbor mixer ----------------
__global__ void mixer_k(const float* __restrict__ x, const float* __restrict__ mw,
                        float* __restrict__ xm)
{
    int idx = blockIdx.x * 256 + threadIdx.x;       // float4 index, total N*D/4
    if (idx >= Nn * Dd / 4) return;
    int d4 = idx & (Dd / 4 - 1);
    int n = idx >> 8;                               // D/4 = 256
    int s = n & (Ss - 1);
    const float4* x4 = (const float4*)x;
    const float4* w4 = (const float4*)mw;
    float4 xc = x4[idx];
    float4 w0 = w4[d4], w1 = w4[(Dd / 4) + d4], w2 = w4[2 * (Dd / 4) + d4];
    float4 o;
    o.x = xc.x * w0.x; o.y = xc.y * w0.y; o.z = xc.z * w0.z; o.w = xc.w * w0.w;
    if (s > 0) {
        float4 xl = x4[idx - Dd / 4];
        o.x += xl.x * w1.x; o.y += xl.y * w1.y; o.z += xl.z * w1.z; o.w += xl.w * w1.w;
    }
    if (s < Ss - 1) {
        float4 xr = x4[idx + Dd / 4];
        o.x += xr.x * w2.x; o.y += xr.y * w2.y; o.z += xr.z * w2.z; o.w += xr.w * w2.w;
    }
    ((float4*)xm)[idx] = o;
}

__global__ void tanh_k(const float* __restrict__ a, float* __restrict__ o, int total)
{
    int idx = blockIdx.x * 256 + threadIdx.x;
    if (idx < total) o[idx] = tanhf(a[idx]);
}

__global__ void addb_k(const float* __restrict__ a, const float* __restrict__ bvec,
                       float* __restrict__ o, int total, int cmask)
{
    int idx = blockIdx.x * 256 + threadIdx.x;
    if (idx < total) o[idx] = a[idx] + bvec[idx & cmask];
}

// ---------------- tiled f32 GEMM: C[r,c] = sum_k A[r,k]*B[k,c] + epilogue ----------------
// EPI 0: +bias (nullable)
// EPI 1: tanh(acc + Cinit)        (obs; b1 folded into zx)
// EPI 2: acc + Cinit + bias       (twist: Cinit=x_mixed, bias=tbr)
// EPI 3: acc + sum_p rw[r,p]*bbr[p,c]; A-load scaled by rw[r, k>>8] if ascale
template<int EPI>
__global__ __launch_bounds__(256)
void gemm_k(const float* __restrict__ A, int lda,
            const float* __restrict__ Bm, int ldb,
            float* __restrict__ C, int ldc,
            const float* __restrict__ Cinit,
            const float* __restrict__ bias,
            const float* __restrict__ rwv,
            const float* __restrict__ bbrv,
            int K, int ascale)
{
    __shared__ float As[16][132];   // transposed: As[k][row]
    __shared__ float Bs[16][132];
    const int r0 = blockIdx.y * 128;
    const int c0 = blockIdx.x * 128;
    const int tid = threadIdx.x;
    const int tc = tid & 15, tr = tid >> 4;

    float acc[8][8];
#pragma unroll
    for (int i = 0; i < 8; ++i)
#pragma unroll
        for (int j = 0; j < 8; ++j) acc[i][j] = 0.f;

    for (int k0 = 0; k0 < K; k0 += 16) {
#pragma unroll
        for (int l = 0; l < 2; ++l) {
            int f = tid + l * 256;
            int row = f >> 2;
            int k4 = (f & 3) << 2;
            float4 av = *(const float4*)(A + (long)(r0 + row) * lda + k0 + k4);
            if (EPI == 3) {
                if (ascale) {
                    float sc = rwv[(long)(r0 + row) * Pp + ((k0 + k4) >> 8)];
                    av.x *= sc; av.y *= sc; av.z *= sc; av.w *= sc;
                }
            }
            As[k4 + 0][row] = av.x; As[k4 + 1][row] = av.y;
            As[k4 + 2][row] = av.z; As[k4 + 3][row] = av.w;
        }
#pragma unroll
        for (int l = 0; l < 2; ++l) {
            int f = tid + l * 256;
            int kr = f >> 5;
            int c4 = (f & 31) << 2;
            *(float4*)(&Bs[kr][c4]) = *(const float4*)(Bm + (long)(k0 + kr) * ldb + c0 + c4);
        }
        __syncthreads();
#pragma unroll
        for (int kk = 0; kk < 16; ++kk) {
            float4 a0 = *(const float4*)(&As[kk][tr * 8]);
            float4 a1 = *(const float4*)(&As[kk][tr * 8 + 4]);
            float4 b0 = *(const float4*)(&Bs[kk][tc * 8]);
            float4 b1 = *(const float4*)(&Bs[kk][tc * 8 + 4]);
            float ar[8] = {a0.x, a0.y, a0.z, a0.w, a1.x, a1.y, a1.z, a1.w};
            float br[8] = {b0.x, b0.y, b0.z, b0.w, b1.x, b1.y, b1.z, b1.w};
#pragma unroll
            for (int i = 0; i < 8; ++i)
#pragma unroll
                for (int j = 0; j < 8; ++j)
                    acc[i][j] += ar[i] * br[j];
        }
        __syncthreads();
    }

#pragma unroll
    for (int i = 0; i < 8; ++i) {
        int r = r0 + tr * 8 + i;
        float rw9[Pp];
        if (EPI == 3) {
#pragma unroll
            for (int p = 0; p < Pp; ++p) rw9[p] = rwv[(long)r * Pp + p];
        }
#pragma unroll
        for (int j = 0; j < 8; ++j) {
            int c = c0 + tc * 8 + j;
            float v = acc[i][j];
            if (EPI == 0) {
                if (bias) v += bias[c];
            } else if (EPI == 1) {
                v = tanhf(v + Cinit[(long)r * ldc + c]);
            } else if (EPI == 2) {
                v += Cinit[(long)r * ldc + c] + bias[c];
            } else if (EPI == 3) {
#pragma unroll
                for (int p = 0; p < Pp; ++p) v += rw9[p] * bbrv[(long)p * ldc + c];
            }
            C[(long)r * ldc + c] = v;
        }
    }
}

// ---------------- logits + softmax (or hard one-hot argmax) ----------------
__global__ void logits_k(const float* __restrict__ h, const float* __restrict__ W2r,
                         const float* __restrict__ b2r, const float* __restrict__ gum,
                         float* __restrict__ rw, int hard)
{
    __shared__ float hs[Mm];
    __shared__ float lg[16];
    int n = blockIdx.x;
    for (int i = threadIdx.x; i < Mm; i += 64) hs[i] = h[(long)n * Mm + i];
    __syncthreads();
    if (threadIdx.x < Pp) {
        int p = threadIdx.x;
        float acc = b2r[p];
        for (int m = 0; m < Mm; ++m) acc += hs[m] * W2r[m * Pp + p];
        lg[p] = acc + gum[(long)n * Pp + p];     // TAU = 1
    }
    __syncthreads();
    if (threadIdx.x == 0) {
        float mx = lg[0]; int am = 0;
#pragma unroll
        for (int p = 1; p < Pp; ++p) if (lg[p] > mx) { mx = lg[p]; am = p; }
        if (hard) {
#pragma unroll
            for (int p = 0; p < Pp; ++p) rw[(long)n * Pp + p] = (p == am) ? 1.f : 0.f;
        } else {
            float e[Pp]; float ssum = 0.f;
#pragma unroll
            for (int p = 0; p < Pp; ++p) { e[p] = expf(lg[p] - mx); ssum += e[p]; }
#pragma unroll
            for (int p = 0; p < Pp; ++p) rw[(long)n * Pp + p] = e[p] / ssum;
        }
    }
}

// ---------------- mod-phase RMS norm (group = d % 7), f32 output ----------------
__global__ void norm_k(const float* __restrict__ in, const float* __restrict__ add,
                       const float* __restrict__ g, float* __restrict__ out)
{
    __shared__ float sb[256][8];
    __shared__ float dn[8];
    int n = blockIdx.x;
    int t = threadIdx.x;
    float v[4];
#pragma unroll
    for (int j = 0; j < 7; ++j) sb[t][j] = 0.f;
#pragma unroll
    for (int i = 0; i < 4; ++i) {
        int d = t + i * 256;
        float xv = in[(long)n * Dd + d];
        if (add) xv += add[(long)n * Dd + d];
        v[i] = xv;
        sb[t][d % 7] += xv * xv;
    }
    __syncthreads();
    for (int st = 128; st >= 1; st >>= 1) {
        if (t < st) {
#pragma unroll
            for (int j = 0; j < 7; ++j) sb[t][j] += sb[t + st][j];
        }
        __syncthreads();
    }
    if (t < 7) {
        const float cnt = (t < 2) ? 147.f : 146.f;
        dn[t] = 1.f / sqrtf(sb[0][t] / cnt + EPSf);
    }
    __syncthreads();
#pragma unroll
    for (int i = 0; i < 4; ++i) {
        int d = t + i * 256;
        out[(long)n * Dd + d] = v[i] * dn[d % 7] * g[d];
    }
}

static inline int cdiv(long a, long b) { return (int)((a + b - 1) / b); }

extern "C" void kernel_launch(void* const* d_in, const int* in_sizes, int n_in,
                              void* d_out, int out_size, void* d_ws, size_t ws_size,
                              hipStream_t stream)
{
    const float* x    = (const float*)d_in[0];
    const float* gum  = (const float*)d_in[1];
    const float* mw   = (const float*)d_in[2];
    const float* W1   = (const float*)d_in[3];
    const float* b1   = (const float*)d_in[4];
    const float* th1  = (const float*)d_in[5];
    const float* W2   = (const float*)d_in[6];
    const float* b2   = (const float*)d_in[7];
    const float* th2  = (const float*)d_in[8];
    const float* Wa   = (const float*)d_in[9];
    const float* ba   = (const float*)d_in[10];
    const float* tha  = (const float*)d_in[11];
    const float* Wb   = (const float*)d_in[12];
    const float* bbv  = (const float*)d_in[13];
    const float* thb  = (const float*)d_in[14];
    const float* tW   = (const float*)d_in[15];
    const float* tb   = (const float*)d_in[16];
    const float* tth  = (const float*)d_in[17];
    const float* gnorm = (const float*)d_in[18];

    float* ws = (float*)d_ws;
    float* xm   = ws;  ws += (long)Nn * Dd;
    float* zx   = ws;  ws += (long)Nn * Mm;
    float* hbuf = ws;  ws += (long)Nn * Mm;
    float* rw   = ws;  ws += (long)Nn * Pp;
    float* tin  = ws;  ws += (long)Nn * Dd;      // doubles as craw / fc_raw
    float* hp   = ws;  ws += (long)Nn * Kcat;
    float* col  = ws;  ws += (long)Nn * Dd;
    float* W1r  = ws;  ws += 2048 * 256;
    float* b1r  = ws;  ws += 256;
    float* W2r  = ws;  ws += 256 * Pp;
    float* b2r  = ws;  ws += 16;
    float* tWr  = ws;  ws += 1024 * 1024;
    float* tbr  = ws;  ws += 1024;
    float* Wac  = ws;  ws += (long)Dd * Kcat;
    float* bac  = ws;  ws += Kcat;
    float* Wbr  = ws;  ws += (long)Kcat * Dd;
    float* bbr  = ws;  ws += Pp * Dd;

    size_t need_bytes = (size_t)(ws - (float*)d_ws) * sizeof(float);
    if (ws_size < need_bytes) return;   // fail loudly (output stays wrong)

    // Reference output dtype is float32 -> d_out is float* (out, collapsed) concat
    float* out0 = (float*)d_out;
    float* out1 = out0 + (long)Nn * Dd;

    // ---- prep: fold all rotations into weights ----
    rotcopy_k<<<cdiv(2048L * 256, 256), 256, 0, stream>>>(W1, W1r, 2048, 256, th1, 1);
    rotcopy_k<<<1, 256, 0, stream>>>(b1, b1r, 1, 256, th1, 1);
    rotcopy_k<<<cdiv(256L * 9, 256), 256, 0, stream>>>(W2, W2r, 256, 9, th2, 1);
    rotcopy_k<<<1, 256, 0, stream>>>(b2, b2r, 1, 9, th2, 1);
    rotcopy_k<<<cdiv(1024L * 1024, 256), 256, 0, stream>>>(tW, tWr, 1024, 1024, tth, 1);
    rotcopy_k<<<cdiv(1024L, 256), 256, 0, stream>>>(tb, tbr, 1, 1024, tth, 1);
    wacat_k<<<cdiv((long)Pp * Dd * Mm, 256), 256, 0, stream>>>(Wa, tha, Wac);
    rotcopy_k<<<cdiv((long)Pp * Mm, 256), 256, 0, stream>>>(ba, bac, 1, 256, tha, 9);
    rotcopy_k<<<cdiv((long)Kcat * Dd, 256), 256, 0, stream>>>(Wb, Wbr, 256, 1024, thb, 9);
    rotcopy_k<<<cdiv((long)Pp * Dd, 256), 256, 0, stream>>>(bbv, bbr, 1, 1024, thb, 9);

    // ---- x_mixed ----
    mixer_k<<<Nn * Dd / 4 / 256, 256, 0, stream>>>(x, mw, xm);

    // ---- zx = x_mixed @ W1_top + b1r (constant across twists) ----
    gemm_k<0><<<dim3(Mm / 128, Nn / 128), 256, 0, stream>>>(
        xm, Dd, W1r, Mm, zx, Mm, nullptr, b1r, nullptr, nullptr, Dd, 0);

    for (int t = 0; t < 3; ++t) {
        // observer hidden: h = tanh(zx + collapsed @ W1_bot)
        if (t == 0) {
            tanh_k<<<cdiv((long)Nn * Mm, 256), 256, 0, stream>>>(zx, hbuf, Nn * Mm);
        } else {
            gemm_k<1><<<dim3(Mm / 128, Nn / 128), 256, 0, stream>>>(
                col, Dd, W1r + 1024 * 256, Mm, hbuf, Mm, zx, nullptr, nullptr, nullptr, Dd, 0);
        }
        // routing weights (soft)
        logits_k<<<Nn, 64, 0, stream>>>(hbuf, W2r, b2r, gum + (long)t * Nn * Pp, rw, 0);
        // tin = x_mixed + rot(collapsed @ twist_W + twist_b)
        if (t == 0) {
            addb_k<<<cdiv((long)Nn * Dd, 256), 256, 0, stream>>>(xm, tbr, tin, Nn * Dd, Dd - 1);
        } else {
            gemm_k<2><<<dim3(Dd / 128, Nn / 128), 256, 0, stream>>>(
                col, Dd, tWr, Dd, tin, Dd, xm, tbr, nullptr, nullptr, Dd, 0);
        }
        // stage A: hp = tin @ Wacat + bacat   (N x 2304)
        gemm_k<0><<<dim3(Kcat / 128, Nn / 128), 256, 0, stream>>>(
            tin, Dd, Wac, Kcat, hp, Kcat, nullptr, bac, nullptr, nullptr, Dd, 0);
        // stage B: craw = (rw*hp) @ Wbr + sum_p rw_p*bbr_p   (writes tin buffer)
        gemm_k<3><<<dim3(Dd / 128, Nn / 128), 256, 0, stream>>>(
            hp, Kcat, Wbr, Dd, tin, Dd, nullptr, nullptr, rw, bbr, Kcat, 1);
        // collapsed = mod_phase_norm(craw)
        norm_k<<<Nn, 256, 0, stream>>>(tin, nullptr, gnorm, col);
    }

    // ---- final hard routing ----
    gemm_k<1><<<dim3(Mm / 128, Nn / 128), 256, 0, stream>>>(
        col, Dd, W1r + 1024 * 256, Mm, hbuf, Mm, zx, nullptr, nullptr, nullptr, Dd, 0);
    logits_k<<<Nn, 64, 0, stream>>>(hbuf, W2r, b2r, gum + 3L * Nn * Pp, rw, 1);
    // fc_raw = (onehot*hp) @ Wbr + bbr[p*]  == path_out[n, p*]
    gemm_k<3><<<dim3(Dd / 128, Nn / 128), 256, 0, stream>>>(
        hp, Kcat, Wbr, Dd, tin, Dd, nullptr, nullptr, rw, bbr, Kcat, 1);
    // out = norm(x + fc_raw);  collapsed_out = norm(collapsed)  (double-norm per reference)
    norm_k<<<Nn, 256, 0, stream>>>(tin, x, gnorm, out0);
    norm_k<<<Nn, 256, 0, stream>>>(col, nullptr, gnorm, out1);
}

// Round 3
// 2030.385 us; speedup vs baseline: 2.3728x; 2.3728x over previous
//
#include <hip/hip_runtime.h>
#include <hip/hip_bf16.h>

// MobiusCollapseLayer: B=4,S=2048,D=1024,P=9,M=256, 3 twists. N=8192 tokens.
// Round 3: all big GEMMs -> split-bf16 (hi+lo) 3-term MFMA (f32-grade accuracy).
typedef unsigned short u16;
typedef short bf16x8 __attribute__((ext_vector_type(8)));
typedef float f32x4 __attribute__((ext_vector_type(4)));

constexpr int Dd = 1024, Pp = 9, Mm = 256, Nn = 8192, Kc = 2304;
constexpr float EPSf = 1e-6f;

__device__ __forceinline__ float bf2f(u16 u) {
    union { unsigned int u; float f; } v; v.u = ((unsigned int)u) << 16; return v.f;
}
__device__ __forceinline__ u16 f2bf(float f) {
    union { float f; unsigned int u; } v; v.f = f;
    unsigned int r = (v.u + 0x7FFFu + ((v.u >> 16) & 1u)) >> 16; return (u16)r;
}
__device__ __forceinline__ void split2(float v, u16& h, u16& l) {
    h = f2bf(v); l = f2bf(v - bf2f(h));
}
__device__ __forceinline__ void gld16(u16* lds, const u16* g) {
    __builtin_amdgcn_global_load_lds(
        (const __attribute__((address_space(1))) unsigned int*)g,
        (__attribute__((address_space(3))) unsigned int*)lds, 16, 0, 0);
}

// ---------------- weight prep: rotate + transpose + split ----------------
__global__ void rotcopy_k(const float* __restrict__ src, float* __restrict__ dst,
                          int R, int C, const float* __restrict__ theta, int Pb)
{
    long total = (long)Pb * R * C;
    long idx = (long)blockIdx.x * 256 + threadIdx.x;
    if (idx >= total) return;
    int c = (int)(idx % C);
    long rp = idx / C;
    int r = (int)(rp % R);
    int pb = (int)(rp / R);
    float th = theta[pb];
    const float* s = src + ((long)pb * R + r) * C;
    float v;
    if (c == 0)      v = s[0] * cosf(th) - s[1] * sinf(th);
    else if (c == 1) v = s[0] * sinf(th) + s[1] * cosf(th);
    else             v = s[c];
    dst[idx] = v;
}

// W1 [2048][256] -> W1t [256 n][2048 k], rot(th1) on n in {0,1}, split
__global__ void splitW1_k(const float* __restrict__ W1, const float* __restrict__ th,
                          u16* __restrict__ h, u16* __restrict__ l)
{
    int idx = blockIdx.x * 256 + threadIdx.x;
    if (idx >= 256 * 2048) return;
    int k = idx & 2047, n = idx >> 11;
    float v;
    if (n == 0)      v = W1[(long)k * 256 + 0] * cosf(th[0]) - W1[(long)k * 256 + 1] * sinf(th[0]);
    else if (n == 1) v = W1[(long)k * 256 + 0] * sinf(th[0]) + W1[(long)k * 256 + 1] * cosf(th[0]);
    else             v = W1[(long)k * 256 + n];
    u16 hh, ll; split2(v, hh, ll); h[idx] = hh; l[idx] = ll;
}

// tW [1024][1024] -> tWt [1024 n][1024 k], rot(tth) on n in {0,1}, split
__global__ void splitTW_k(const float* __restrict__ tW, const float* __restrict__ th,
                          u16* __restrict__ h, u16* __restrict__ l)
{
    int idx = blockIdx.x * 256 + threadIdx.x;
    if (idx >= 1024 * 1024) return;
    int k = idx & 1023, n = idx >> 10;
    float v;
    if (n == 0)      v = tW[(long)k * 1024 + 0] * cosf(th[0]) - tW[(long)k * 1024 + 1] * sinf(th[0]);
    else if (n == 1) v = tW[(long)k * 1024 + 0] * sinf(th[0]) + tW[(long)k * 1024 + 1] * cosf(th[0]);
    else             v = tW[(long)k * 1024 + n];
    u16 hh, ll; split2(v, hh, ll); h[idx] = hh; l[idx] = ll;
}

// Wa [9][1024 d][256 m] -> Wat [2304 n=p*256+m][1024 k=d], rot(tha[p]) on m in {0,1}
__global__ void splitWa_k(const float* __restrict__ Wa, const float* __restrict__ tha,
                          u16* __restrict__ h, u16* __restrict__ l)
{
    int idx = blockIdx.x * 256 + threadIdx.x;
    if (idx >= Kc * 1024) return;
    int k = idx & 1023, n = idx >> 10;
    int p = n >> 8, m = n & 255;
    const float* s = Wa + ((long)p * 1024 + k) * 256;
    float v;
    if (m == 0)      v = s[0] * cosf(tha[p]) - s[1] * sinf(tha[p]);
    else if (m == 1) v = s[0] * sinf(tha[p]) + s[1] * cosf(tha[p]);
    else             v = s[m];
    u16 hh, ll; split2(v, hh, ll); h[idx] = hh; l[idx] = ll;
}

// Wb [9][256 m][1024 d] -> Wbt [1024 n=d][2304 k=p*256+m], rot(thb[p]) on d in {0,1}
__global__ void splitWb_k(const float* __restrict__ Wb, const float* __restrict__ thb,
                          u16* __restrict__ h, u16* __restrict__ l)
{
    int idx = blockIdx.x * 256 + threadIdx.x;
    if (idx >= 1024 * Kc) return;
    int n = idx / Kc;              // d
    int k = idx - n * Kc;          // p*256+m
    int p = k >> 8, m = k & 255;
    const float* s = Wb + ((long)p * 256 + m) * 1024;
    float v;
    if (n == 0)      v = s[0] * cosf(thb[p]) - s[1] * sinf(thb[p]);
    else if (n == 1) v = s[0] * sinf(thb[p]) + s[1] * cosf(thb[p]);
    else             v = s[n];
    u16 hh, ll; split2(v, hh, ll); h[idx] = hh; l[idx] = ll;
}

// ---------------- neighbor mixer -> split bf16 ----------------
__global__ void mixer_k(const float* __restrict__ x, const float* __restrict__ mw,
                        u16* __restrict__ xmh, u16* __restrict__ xml)
{
    int idx = blockIdx.x * 256 + threadIdx.x;       // float4 index, total N*D/4
    if (idx >= Nn * Dd / 4) return;
    int d4 = idx & (Dd / 4 - 1);
    int n = idx >> 8;
    int s = n & 2047;                               // S=2048
    const float4* x4 = (const float4*)x;
    const float4* w4 = (const float4*)mw;
    float4 xc = x4[idx];
    float4 w0 = w4[d4], w1 = w4[(Dd / 4) + d4], w2 = w4[2 * (Dd / 4) + d4];
    float o[4];
    o[0] = xc.x * w0.x; o[1] = xc.y * w0.y; o[2] = xc.z * w0.z; o[3] = xc.w * w0.w;
    if (s > 0) {
        float4 xl = x4[idx - Dd / 4];
        o[0] += xl.x * w1.x; o[1] += xl.y * w1.y; o[2] += xl.z * w1.z; o[3] += xl.w * w1.w;
    }
    if (s < 2047) {
        float4 xr = x4[idx + Dd / 4];
        o[0] += xr.x * w2.x; o[1] += xr.y * w2.y; o[2] += xr.z * w2.z; o[3] += xr.w * w2.w;
    }
    ushort4 h4, l4;
    split2(o[0], h4.x, l4.x); split2(o[1], h4.y, l4.y);
    split2(o[2], h4.z, l4.z); split2(o[3], h4.w, l4.w);
    ((ushort4*)xmh)[idx] = h4; ((ushort4*)xml)[idx] = l4;
}

__global__ void tanh_k(const float* __restrict__ a, float* __restrict__ o, int total)
{
    int idx = blockIdx.x * 256 + threadIdx.x;
    if (idx < total) o[idx] = tanhf(a[idx]);
}

// tin = recompose(xm) + tbr  -> split
__global__ void addb_split_k(const u16* __restrict__ xmh, const u16* __restrict__ xml,
                             const float* __restrict__ tbr,
                             u16* __restrict__ th_, u16* __restrict__ tl_)
{
    int idx = blockIdx.x * 256 + threadIdx.x;   // ushort4 index over N*D/4
    if (idx >= Nn * Dd / 4) return;
    int d4 = idx & (Dd / 4 - 1);
    ushort4 xh = ((const ushort4*)xmh)[idx], xl = ((const ushort4*)xml)[idx];
    float4 b = ((const float4*)tbr)[d4];
    ushort4 h4, l4;
    split2(bf2f(xh.x) + bf2f(xl.x) + b.x, h4.x, l4.x);
    split2(bf2f(xh.y) + bf2f(xl.y) + b.y, h4.y, l4.y);
    split2(bf2f(xh.z) + bf2f(xl.z) + b.z, h4.z, l4.z);
    split2(bf2f(xh.w) + bf2f(xl.w) + b.w, h4.w, l4.w);
    ((ushort4*)th_)[idx] = h4; ((ushort4*)tl_)[idx] = l4;
}

// ---------------- split-bf16 MFMA GEMM: C = A x B^T(stored [n][k]) ----------------
// 128x128 tile, BK=32, 4 waves (64x64 each), 4x4 frags of 16x16x32, 3-term split.
// EPI 0: +bias -> f32            (zx)
// EPI 1: tanh(acc + Cinit) ->f32 (obs)
// EPI 2: acc + CIsplit + bias -> split out (twist)
// EPI 3: acc + bias -> split out (stage A)
// EPI 4: per-256K-block rescale by rw[r][p]; + sum_p rw*bbr -> f32 (stage B)
template<int EPI>
__global__ __launch_bounds__(256) void mgemm(
    const u16* __restrict__ Agh, const u16* __restrict__ Agl, int lda,
    const u16* __restrict__ Bgh, const u16* __restrict__ Bgl, int ldb,
    int K,
    float* __restrict__ Cf, u16* __restrict__ Coh, u16* __restrict__ Col, int ldc,
    const float* __restrict__ Cinit,
    const u16* __restrict__ CIh, const u16* __restrict__ CIl,
    const float* __restrict__ bias,
    const float* __restrict__ rwv,
    const float* __restrict__ bbrv)
{
    __shared__ u16 smem[16384];                 // Ah|Al|Bh|Bl, each 128x32 bf16 = 8KB
    u16* As_h = smem;        u16* As_l = smem + 4096;
    u16* Bs_h = smem + 8192; u16* Bs_l = smem + 12288;
    const int tid = threadIdx.x, wave = tid >> 6, lane = tid & 63;
    const int r0 = blockIdx.y * 128, c0 = blockIdx.x * 128;
    // staging lane constants (pre-swizzled global source; linear LDS dest)
    const int srl = lane >> 2;
    const int ssl = ((lane & 3) ^ ((lane >> 3) & 3)) * 8;
    // fragment read constants (swizzled ds_read: slot = k16 ^ ((row>>1)&3))
    const int frl = lane & 15, kh = lane >> 4;
    const int sw  = (kh ^ ((frl >> 1) & 3)) * 8;
    const int arow0 = (wave >> 1) * 64, bcol0 = (wave & 1) * 64;
    const int w32 = wave * 32;

    f32x4 acc[4][4] = {};

    auto kstep = [&](f32x4 (&ac)[4][4], int k0) {
        {
            const long ga0 = (long)(r0 + w32 + srl) * lda + k0 + ssl;
            gld16(&As_h[w32 * 32],        Agh + ga0);
            gld16(&As_h[(w32 + 16) * 32], Agh + ga0 + 16L * lda);
            gld16(&As_l[w32 * 32],        Agl + ga0);
            gld16(&As_l[(w32 + 16) * 32], Agl + ga0 + 16L * lda);
            const long gb0 = (long)(c0 + w32 + srl) * ldb + k0 + ssl;
            gld16(&Bs_h[w32 * 32],        Bgh + gb0);
            gld16(&Bs_h[(w32 + 16) * 32], Bgh + gb0 + 16L * ldb);
            gld16(&Bs_l[w32 * 32],        Bgl + gb0);
            gld16(&Bs_l[(w32 + 16) * 32], Bgl + gb0 + 16L * ldb);
        }
        __syncthreads();
        bf16x8 ah[4], al[4], bh[4], bl[4];
#pragma unroll
        for (int f = 0; f < 4; ++f) {
            int ao = (arow0 + f * 16 + frl) * 32 + sw;
            ah[f] = *(const bf16x8*)&As_h[ao];
            al[f] = *(const bf16x8*)&As_l[ao];
            int bo = (bcol0 + f * 16 + frl) * 32 + sw;
            bh[f] = *(const bf16x8*)&Bs_h[bo];
            bl[f] = *(const bf16x8*)&Bs_l[bo];
        }
#pragma unroll
        for (int i = 0; i < 4; ++i)
#pragma unroll
            for (int j = 0; j < 4; ++j) {
                ac[i][j] = __builtin_amdgcn_mfma_f32_16x16x32_bf16(ah[i], bh[j], ac[i][j], 0, 0, 0);
                ac[i][j] = __builtin_amdgcn_mfma_f32_16x16x32_bf16(ah[i], bl[j], ac[i][j], 0, 0, 0);
                ac[i][j] = __builtin_amdgcn_mfma_f32_16x16x32_bf16(al[i], bh[j], ac[i][j], 0, 0, 0);
            }
        __syncthreads();
    };

    if constexpr (EPI == 4) {
#pragma unroll 1
        for (int p = 0; p < 9; ++p) {
            f32x4 acc2[4][4] = {};
#pragma unroll 1
            for (int ks = 0; ks < 8; ++ks) kstep(acc2, p * 256 + ks * 32);
#pragma unroll
            for (int i = 0; i < 4; ++i)
#pragma unroll
                for (int reg = 0; reg < 4; ++reg) {
                    float w = rwv[(long)(r0 + arow0 + i * 16 + kh * 4 + reg) * 9 + p];
#pragma unroll
                    for (int j = 0; j < 4; ++j) acc[i][j][reg] += w * acc2[i][j][reg];
                }
        }
    } else {
#pragma unroll 1
        for (int k0 = 0; k0 < K; k0 += 32) kstep(acc, k0);
    }

#pragma unroll
    for (int i = 0; i < 4; ++i)
#pragma unroll
        for (int reg = 0; reg < 4; ++reg) {
            const int r = r0 + arow0 + i * 16 + kh * 4 + reg;
#pragma unroll
            for (int j = 0; j < 4; ++j) {
                const int c = c0 + bcol0 + j * 16 + frl;
                float v = acc[i][j][reg];
                if constexpr (EPI == 0) {
                    Cf[(long)r * ldc + c] = v + bias[c];
                } else if constexpr (EPI == 1) {
                    Cf[(long)r * ldc + c] = tanhf(v + Cinit[(long)r * ldc + c]);
                } else if constexpr (EPI == 2) {
                    long o = (long)r * ldc + c;
                    v += bf2f(CIh[o]) + bf2f(CIl[o]) + bias[c];
                    u16 h, l; split2(v, h, l); Coh[o] = h; Col[o] = l;
                } else if constexpr (EPI == 3) {
                    long o = (long)r * ldc + c;
                    v += bias[c];
                    u16 h, l; split2(v, h, l); Coh[o] = h; Col[o] = l;
                } else {
#pragma unroll
                    for (int p = 0; p < 9; ++p) v += rwv[(long)r * 9 + p] * bbrv[p * 1024 + c];
                    Cf[(long)r * ldc + c] = v;
                }
            }
        }
}

// ---------------- logits + softmax / hard one-hot ----------------
__global__ void logits_k(const float* __restrict__ h, const float* __restrict__ W2r,
                         const float* __restrict__ b2r, const float* __restrict__ gum,
                         float* __restrict__ rw, int hard)
{
    __shared__ float hs[Mm];
    __shared__ float lg[16];
    int n = blockIdx.x;
    for (int i = threadIdx.x; i < Mm; i += 64) hs[i] = h[(long)n * Mm + i];
    __syncthreads();
    if (threadIdx.x < Pp) {
        int p = threadIdx.x;
        float acc = b2r[p];
        for (int m = 0; m < Mm; ++m) acc += hs[m] * W2r[m * Pp + p];
        lg[p] = acc + gum[(long)n * Pp + p];
    }
    __syncthreads();
    if (threadIdx.x == 0) {
        float mx = lg[0]; int am = 0;
#pragma unroll
        for (int p = 1; p < Pp; ++p) if (lg[p] > mx) { mx = lg[p]; am = p; }
        if (hard) {
#pragma unroll
            for (int p = 0; p < Pp; ++p) rw[(long)n * Pp + p] = (p == am) ? 1.f : 0.f;
        } else {
            float e[Pp]; float ssum = 0.f;
#pragma unroll
            for (int p = 0; p < Pp; ++p) { e[p] = expf(lg[p] - mx); ssum += e[p]; }
#pragma unroll
            for (int p = 0; p < Pp; ++p) rw[(long)n * Pp + p] = e[p] / ssum;
        }
    }
}

// ---------------- mod-phase RMS norm (group = d % 7) ----------------
// INSPLIT: input from (inh,inl) recomposed, else f32 in. OUTSPLIT: write split, else f32.
template<int INSPLIT, int OUTSPLIT>
__global__ void norm_k(const float* __restrict__ in,
                       const u16* __restrict__ inh, const u16* __restrict__ inl,
                       const float* __restrict__ add, const float* __restrict__ g,
                       float* __restrict__ outf, u16* __restrict__ oh, u16* __restrict__ ol)
{
    __shared__ float sb[256][8];
    __shared__ float dn[8];
    int n = blockIdx.x;
    int t = threadIdx.x;
    float v[4];
#pragma unroll
    for (int j = 0; j < 7; ++j) sb[t][j] = 0.f;
#pragma unroll
    for (int i = 0; i < 4; ++i) {
        int d = t + i * 256;
        long o = (long)n * Dd + d;
        float xv = INSPLIT ? (bf2f(inh[o]) + bf2f(inl[o])) : in[o];
        if (add) xv += add[o];
        v[i] = xv;
        sb[t][d % 7] += xv * xv;
    }
    __syncthreads();
    for (int st = 128; st >= 1; st >>= 1) {
        if (t < st) {
#pragma unroll
            for (int j = 0; j < 7; ++j) sb[t][j] += sb[t + st][j];
        }
        __syncthreads();
    }
    if (t < 7) {
        const float cnt = (t < 2) ? 147.f : 146.f;
        dn[t] = 1.f / sqrtf(sb[0][t] / cnt + EPSf);
    }
    __syncthreads();
#pragma unroll
    for (int i = 0; i < 4; ++i) {
        int d = t + i * 256;
        long o = (long)n * Dd + d;
        float ov = v[i] * dn[d % 7] * g[d];
        if (OUTSPLIT) { u16 h, l; split2(ov, h, l); oh[o] = h; ol[o] = l; }
        else outf[o] = ov;
    }
}

static inline int cdiv(long a, long b) { return (int)((a + b - 1) / b); }

extern "C" void kernel_launch(void* const* d_in, const int* in_sizes, int n_in,
                              void* d_out, int out_size, void* d_ws, size_t ws_size,
                              hipStream_t stream)
{
    const float* x    = (const float*)d_in[0];
    const float* gum  = (const float*)d_in[1];
    const float* mw   = (const float*)d_in[2];
    const float* W1   = (const float*)d_in[3];
    const float* b1   = (const float*)d_in[4];
    const float* th1  = (const float*)d_in[5];
    const float* W2   = (const float*)d_in[6];
    const float* b2   = (const float*)d_in[7];
    const float* th2  = (const float*)d_in[8];
    const float* Wa   = (const float*)d_in[9];
    const float* ba   = (const float*)d_in[10];
    const float* tha  = (const float*)d_in[11];
    const float* Wb   = (const float*)d_in[12];
    const float* bbv  = (const float*)d_in[13];
    const float* thb  = (const float*)d_in[14];
    const float* tW   = (const float*)d_in[15];
    const float* tb   = (const float*)d_in[16];
    const float* tth  = (const float*)d_in[17];
    const float* gnorm = (const float*)d_in[18];

    char* cur = (char*)d_ws;
    auto alloc = [&](size_t bytes) -> void* {
        void* r = (void*)cur; cur += (bytes + 255) & ~(size_t)255; return r;
    };
    // region: craw f32 (8M) == {tinh|tinl} ushorts == hbuf f32 (2M) - phase-disjoint
    void* region = alloc((size_t)Nn * Dd * 4);
    float* craw = (float*)region;
    float* hbuf = (float*)region;
    u16*   tinh = (u16*)region;
    u16*   tinl = tinh + (size_t)Nn * Dd;
    float* zx   = (float*)alloc((size_t)Nn * Mm * 4);
    float* rw   = (float*)alloc((size_t)Nn * Pp * 4);
    u16* xmh  = (u16*)alloc((size_t)Nn * Dd * 2);
    u16* xml  = (u16*)alloc((size_t)Nn * Dd * 2);
    u16* colh = (u16*)alloc((size_t)Nn * Dd * 2);
    u16* coll = (u16*)alloc((size_t)Nn * Dd * 2);
    u16* hph  = (u16*)alloc((size_t)Nn * Kc * 2);
    u16* hpl  = (u16*)alloc((size_t)Nn * Kc * 2);
    u16* W1th = (u16*)alloc(256 * 2048 * 2);
    u16* W1tl = (u16*)alloc(256 * 2048 * 2);
    u16* tWth = (u16*)alloc(1024 * 1024 * 2);
    u16* tWtl = (u16*)alloc(1024 * 1024 * 2);
    u16* Wath = (u16*)alloc((size_t)Kc * 1024 * 2);
    u16* Watl = (u16*)alloc((size_t)Kc * 1024 * 2);
    u16* Wbth = (u16*)alloc((size_t)1024 * Kc * 2);
    u16* Wbtl = (u16*)alloc((size_t)1024 * Kc * 2);
    float* W2r = (float*)alloc(256 * 9 * 4);
    float* b1r = (float*)alloc(256 * 4);
    float* b2r = (float*)alloc(16 * 4);
    float* bac = (float*)alloc(Kc * 4);
    float* bbr = (float*)alloc(Pp * 1024 * 4);
    float* tbr = (float*)alloc(1024 * 4);
    if ((size_t)(cur - (char*)d_ws) > ws_size) return;

    float* out0 = (float*)d_out;
    float* out1 = out0 + (long)Nn * Dd;

    // ---- prep: fold rotations, transpose, split ----
    splitW1_k<<<2048, 256, 0, stream>>>(W1, th1, W1th, W1tl);
    splitTW_k<<<4096, 256, 0, stream>>>(tW, tth, tWth, tWtl);
    splitWa_k<<<cdiv((long)Kc * 1024, 256), 256, 0, stream>>>(Wa, tha, Wath, Watl);
    splitWb_k<<<cdiv((long)1024 * Kc, 256), 256, 0, stream>>>(Wb, thb, Wbth, Wbtl);
    rotcopy_k<<<cdiv(256L * 9, 256), 256, 0, stream>>>(W2, W2r, 256, 9, th2, 1);
    rotcopy_k<<<1, 256, 0, stream>>>(b1, b1r, 1, 256, th1, 1);
    rotcopy_k<<<1, 256, 0, stream>>>(b2, b2r, 1, 9, th2, 1);
    rotcopy_k<<<cdiv((long)Pp * Mm, 256), 256, 0, stream>>>(ba, bac, 1, 256, tha, 9);
    rotcopy_k<<<cdiv((long)Pp * 1024, 256), 256, 0, stream>>>(bbv, bbr, 1, 1024, thb, 9);
    rotcopy_k<<<cdiv(1024L, 256), 256, 0, stream>>>(tb, tbr, 1, 1024, tth, 1);

    // ---- x_mixed (split) ----
    mixer_k<<<Nn * Dd / 4 / 256, 256, 0, stream>>>(x, mw, xmh, xml);

    // ---- zx = x_mixed @ W1_top + b1r ----
    mgemm<0><<<dim3(2, 64), 256, 0, stream>>>(
        xmh, xml, 1024, W1th, W1tl, 2048, 1024,
        zx, nullptr, nullptr, 256, nullptr, nullptr, nullptr, b1r, nullptr, nullptr);

    for (int t = 0; t < 3; ++t) {
        if (t == 0) {
            tanh_k<<<cdiv((long)Nn * Mm, 256), 256, 0, stream>>>(zx, hbuf, Nn * Mm);
        } else {
            mgemm<1><<<dim3(2, 64), 256, 0, stream>>>(
                colh, coll, 1024, W1th + 1024, W1tl + 1024, 2048, 1024,
                hbuf, nullptr, nullptr, 256, zx, nullptr, nullptr, nullptr, nullptr, nullptr);
        }
        logits_k<<<Nn, 64, 0, stream>>>(hbuf, W2r, b2r, gum + (long)t * Nn * Pp, rw, 0);
        if (t == 0) {
            addb_split_k<<<Nn * Dd / 4 / 256, 256, 0, stream>>>(xmh, xml, tbr, tinh, tinl);
        } else {
            mgemm<2><<<dim3(8, 64), 256, 0, stream>>>(
                colh, coll, 1024, tWth, tWtl, 1024, 1024,
                nullptr, tinh, tinl, 1024, nullptr, xmh, xml, tbr, nullptr, nullptr);
        }
        // stage A: hp = tin @ Wat + bac (split out)
        mgemm<3><<<dim3(18, 64), 256, 0, stream>>>(
            tinh, tinl, 1024, Wath, Watl, 1024, 1024,
            nullptr, hph, hpl, Kc, nullptr, nullptr, nullptr, bac, nullptr, nullptr);
        // stage B: craw = sum_p rw_p (hp_p @ Wbt_p) + sum_p rw_p bbr_p
        mgemm<4><<<dim3(8, 64), 256, 0, stream>>>(
            hph, hpl, Kc, Wbth, Wbtl, Kc, Kc,
            craw, nullptr, nullptr, 1024, nullptr, nullptr, nullptr, nullptr, rw, bbr);
        // collapsed = mod_phase_norm(craw) -> split
        norm_k<0, 1><<<Nn, 256, 0, stream>>>(craw, nullptr, nullptr, nullptr, gnorm,
                                             nullptr, colh, coll);
    }

    // ---- final hard routing ----
    mgemm<1><<<dim3(2, 64), 256, 0, stream>>>(
        colh, coll, 1024, W1th + 1024, W1tl + 1024, 2048, 1024,
        hbuf, nullptr, nullptr, 256, zx, nullptr, nullptr, nullptr, nullptr, nullptr);
    logits_k<<<Nn, 64, 0, stream>>>(hbuf, W2r, b2r, gum + 3L * Nn * Pp, rw, 1);
    mgemm<4><<<dim3(8, 64), 256, 0, stream>>>(
        hph, hpl, Kc, Wbth, Wbtl, Kc, Kc,
        craw, nullptr, nullptr, 1024, nullptr, nullptr, nullptr, nullptr, rw, bbr);
    // out0 = norm(x + fc_raw); out1 = norm(collapsed)
    norm_k<0, 0><<<Nn, 256, 0, stream>>>(craw, nullptr, nullptr, x, gnorm, out0, nullptr, nullptr);
    norm_k<1, 0><<<Nn, 256, 0, stream>>>(nullptr, colh, coll, nullptr, gnorm, out1, nullptr, nullptr);
}

// Round 4
// 1448.370 us; speedup vs baseline: 3.3263x; 1.4018x over previous
//
#include <hip/hip_runtime.h>
#include <hip/hip_bf16.h>

// MobiusCollapseLayer: B=4,S=2048,D=1024,P=9,M=256, 3 twists. N=8192 tokens.
// Round 4: fold rw into stage-A epilogue; stage-B -> plain GEMM; final uses
// rw_hard/rw_soft2 ratio; VGPR diet (+launch_bounds 3 waves/SIMD); XCD swizzle.
typedef unsigned short u16;
typedef short bf16x8 __attribute__((ext_vector_type(8)));
typedef float f32x4 __attribute__((ext_vector_type(4)));

constexpr int Dd = 1024, Pp = 9, Mm = 256, Nn = 8192, Kc = 2304;
constexpr float EPSf = 1e-6f;

__device__ __forceinline__ float bf2f(u16 u) {
    union { unsigned int u; float f; } v; v.u = ((unsigned int)u) << 16; return v.f;
}
__device__ __forceinline__ u16 f2bf(float f) {
    union { float f; unsigned int u; } v; v.f = f;
    unsigned int r = (v.u + 0x7FFFu + ((v.u >> 16) & 1u)) >> 16; return (u16)r;
}
__device__ __forceinline__ void split2(float v, u16& h, u16& l) {
    h = f2bf(v); l = f2bf(v - bf2f(h));
}
__device__ __forceinline__ void gld16(u16* lds, const u16* g) {
    __builtin_amdgcn_global_load_lds(
        (const __attribute__((address_space(1))) unsigned int*)g,
        (__attribute__((address_space(3))) unsigned int*)lds, 16, 0, 0);
}

// ---------------- weight prep: rotate + transpose + split ----------------
__global__ void rotcopy_k(const float* __restrict__ src, float* __restrict__ dst,
                          int R, int C, const float* __restrict__ theta, int Pb)
{
    long total = (long)Pb * R * C;
    long idx = (long)blockIdx.x * 256 + threadIdx.x;
    if (idx >= total) return;
    int c = (int)(idx % C);
    long rp = idx / C;
    int r = (int)(rp % R);
    int pb = (int)(rp / R);
    float th = theta[pb];
    const float* s = src + ((long)pb * R + r) * C;
    float v;
    if (c == 0)      v = s[0] * cosf(th) - s[1] * sinf(th);
    else if (c == 1) v = s[0] * sinf(th) + s[1] * cosf(th);
    else             v = s[c];
    dst[idx] = v;
}

__global__ void splitW1_k(const float* __restrict__ W1, const float* __restrict__ th,
                          u16* __restrict__ h, u16* __restrict__ l)
{
    int idx = blockIdx.x * 256 + threadIdx.x;
    if (idx >= 256 * 2048) return;
    int k = idx & 2047, n = idx >> 11;
    float v;
    if (n == 0)      v = W1[(long)k * 256 + 0] * cosf(th[0]) - W1[(long)k * 256 + 1] * sinf(th[0]);
    else if (n == 1) v = W1[(long)k * 256 + 0] * sinf(th[0]) + W1[(long)k * 256 + 1] * cosf(th[0]);
    else             v = W1[(long)k * 256 + n];
    u16 hh, ll; split2(v, hh, ll); h[idx] = hh; l[idx] = ll;
}

__global__ void splitTW_k(const float* __restrict__ tW, const float* __restrict__ th,
                          u16* __restrict__ h, u16* __restrict__ l)
{
    int idx = blockIdx.x * 256 + threadIdx.x;
    if (idx >= 1024 * 1024) return;
    int k = idx & 1023, n = idx >> 10;
    float v;
    if (n == 0)      v = tW[(long)k * 1024 + 0] * cosf(th[0]) - tW[(long)k * 1024 + 1] * sinf(th[0]);
    else if (n == 1) v = tW[(long)k * 1024 + 0] * sinf(th[0]) + tW[(long)k * 1024 + 1] * cosf(th[0]);
    else             v = tW[(long)k * 1024 + n];
    u16 hh, ll; split2(v, hh, ll); h[idx] = hh; l[idx] = ll;
}

__global__ void splitWa_k(const float* __restrict__ Wa, const float* __restrict__ tha,
                          u16* __restrict__ h, u16* __restrict__ l)
{
    int idx = blockIdx.x * 256 + threadIdx.x;
    if (idx >= Kc * 1024) return;
    int k = idx & 1023, n = idx >> 10;
    int p = n >> 8, m = n & 255;
    const float* s = Wa + ((long)p * 1024 + k) * 256;
    float v;
    if (m == 0)      v = s[0] * cosf(tha[p]) - s[1] * sinf(tha[p]);
    else if (m == 1) v = s[0] * sinf(tha[p]) + s[1] * cosf(tha[p]);
    else             v = s[m];
    u16 hh, ll; split2(v, hh, ll); h[idx] = hh; l[idx] = ll;
}

__global__ void splitWb_k(const float* __restrict__ Wb, const float* __restrict__ thb,
                          u16* __restrict__ h, u16* __restrict__ l)
{
    int idx = blockIdx.x * 256 + threadIdx.x;
    if (idx >= 1024 * Kc) return;
    int n = idx / Kc;              // d
    int k = idx - n * Kc;          // p*256+m
    int p = k >> 8, m = k & 255;
    const float* s = Wb + ((long)p * 256 + m) * 1024;
    float v;
    if (n == 0)      v = s[0] * cosf(thb[p]) - s[1] * sinf(thb[p]);
    else if (n == 1) v = s[0] * sinf(thb[p]) + s[1] * cosf(thb[p]);
    else             v = s[n];
    u16 hh, ll; split2(v, hh, ll); h[idx] = hh; l[idx] = ll;
}

// ---------------- neighbor mixer -> split bf16 ----------------
__global__ void mixer_k(const float* __restrict__ x, const float* __restrict__ mw,
                        u16* __restrict__ xmh, u16* __restrict__ xml)
{
    int idx = blockIdx.x * 256 + threadIdx.x;       // float4 index, total N*D/4
    if (idx >= Nn * Dd / 4) return;
    int d4 = idx & (Dd / 4 - 1);
    int n = idx >> 8;
    int s = n & 2047;                               // S=2048
    const float4* x4 = (const float4*)x;
    const float4* w4 = (const float4*)mw;
    float4 xc = x4[idx];
    float4 w0 = w4[d4], w1 = w4[(Dd / 4) + d4], w2 = w4[2 * (Dd / 4) + d4];
    float o[4];
    o[0] = xc.x * w0.x; o[1] = xc.y * w0.y; o[2] = xc.z * w0.z; o[3] = xc.w * w0.w;
    if (s > 0) {
        float4 xl = x4[idx - Dd / 4];
        o[0] += xl.x * w1.x; o[1] += xl.y * w1.y; o[2] += xl.z * w1.z; o[3] += xl.w * w1.w;
    }
    if (s < 2047) {
        float4 xr = x4[idx + Dd / 4];
        o[0] += xr.x * w2.x; o[1] += xr.y * w2.y; o[2] += xr.z * w2.z; o[3] += xr.w * w2.w;
    }
    ushort4 h4, l4;
    split2(o[0], h4.x, l4.x); split2(o[1], h4.y, l4.y);
    split2(o[2], h4.z, l4.z); split2(o[3], h4.w, l4.w);
    ((ushort4*)xmh)[idx] = h4; ((ushort4*)xml)[idx] = l4;
}

__global__ void tanh_k(const float* __restrict__ a, float* __restrict__ o, int total)
{
    int idx = blockIdx.x * 256 + threadIdx.x;
    if (idx < total) o[idx] = tanhf(a[idx]);
}

__global__ void addb_split_k(const u16* __restrict__ xmh, const u16* __restrict__ xml,
                             const float* __restrict__ tbr,
                             u16* __restrict__ th_, u16* __restrict__ tl_)
{
    int idx = blockIdx.x * 256 + threadIdx.x;   // ushort4 index over N*D/4
    if (idx >= Nn * Dd / 4) return;
    int d4 = idx & (Dd / 4 - 1);
    ushort4 xh = ((const ushort4*)xmh)[idx], xl = ((const ushort4*)xml)[idx];
    float4 b = ((const float4*)tbr)[d4];
    ushort4 h4, l4;
    split2(bf2f(xh.x) + bf2f(xl.x) + b.x, h4.x, l4.x);
    split2(bf2f(xh.y) + bf2f(xl.y) + b.y, h4.y, l4.y);
    split2(bf2f(xh.z) + bf2f(xl.z) + b.z, h4.z, l4.z);
    split2(bf2f(xh.w) + bf2f(xl.w) + b.w, h4.w, l4.w);
    ((ushort4*)th_)[idx] = h4; ((ushort4*)tl_)[idx] = l4;
}

// ---------------- split-bf16 MFMA GEMM: C = A x B^T(stored [n][k]) ----------------
// 128x128 tile, BK=32, 4 waves (64x64), 4x4 frags 16x16x32, 3-term split.
// EPI 0: +bias -> f32                       (zx)
// EPI 1: tanh(acc + Cinit) -> f32           (obs)
// EPI 2: acc + CIsplit + bias -> split out  (twist)
// EPI 3: (acc + bias) * rw[r][c>>8] -> split out  (stage A, rw-folded)
// EPI 4: per-256K-block scale by rwv (=rw_hard/rw_soft2); + sum_p rwv2*bbr (final)
// EPI 5: acc + sum_p rwv*bbr -> f32         (stage B twists, plain K=2304)
template<int EPI>
__global__ __launch_bounds__(256, (EPI == 4) ? 2 : 3) void mgemm(
    const u16* __restrict__ Agh, const u16* __restrict__ Agl, int lda,
    const u16* __restrict__ Bgh, const u16* __restrict__ Bgl, int ldb,
    int K,
    float* __restrict__ Cf, u16* __restrict__ Coh, u16* __restrict__ Col, int ldc,
    const float* __restrict__ Cinit,
    const u16* __restrict__ CIh, const u16* __restrict__ CIl,
    const float* __restrict__ bias,
    const float* __restrict__ rwv,
    const float* __restrict__ rwv2,
    const float* __restrict__ bbrv)
{
    __shared__ u16 smem[16384];                 // Ah|Al|Bh|Bl, each 128x32 bf16 = 8KB
    u16* As_h = smem;        u16* As_l = smem + 4096;
    u16* Bs_h = smem + 8192; u16* Bs_l = smem + 12288;
    const int tid = threadIdx.x, wave = tid >> 6, lane = tid & 63;
    // T1: XCD-aware swizzle (all grids are multiples of 8 blocks)
    const int nwg = gridDim.x * gridDim.y;
    const int flat = blockIdx.y * gridDim.x + blockIdx.x;
    const int q = nwg >> 3;
    const int l_ = (flat & 7) * q + (flat >> 3);
    const int r0 = (l_ / gridDim.x) * 128, c0 = (l_ % gridDim.x) * 128;
    // staging lane constants (pre-swizzled global source; linear LDS dest)
    const int srl = lane >> 2;
    const int ssl = ((lane & 3) ^ ((lane >> 3) & 3)) * 8;
    // fragment read constants (swizzled ds_read: slot = k16 ^ ((row>>1)&3))
    const int frl = lane & 15, kh = lane >> 4;
    const int sw  = (kh ^ ((frl >> 1) & 3)) * 8;
    const int arow0 = (wave >> 1) * 64, bcol0 = (wave & 1) * 64;
    const int w32 = wave * 32;

    f32x4 acc[4][4] = {};

    auto kstep = [&](f32x4 (&ac)[4][4], int k0) {
        {
            const long ga0 = (long)(r0 + w32 + srl) * lda + k0 + ssl;
            gld16(&As_h[w32 * 32],        Agh + ga0);
            gld16(&As_h[(w32 + 16) * 32], Agh + ga0 + 16L * lda);
            gld16(&As_l[w32 * 32],        Agl + ga0);
            gld16(&As_l[(w32 + 16) * 32], Agl + ga0 + 16L * lda);
            const long gb0 = (long)(c0 + w32 + srl) * ldb + k0 + ssl;
            gld16(&Bs_h[w32 * 32],        Bgh + gb0);
            gld16(&Bs_h[(w32 + 16) * 32], Bgh + gb0 + 16L * ldb);
            gld16(&Bs_l[w32 * 32],        Bgl + gb0);
            gld16(&Bs_l[(w32 + 16) * 32], Bgl + gb0 + 16L * ldb);
        }
        __syncthreads();
        bf16x8 ah[4], al[4];
#pragma unroll
        for (int f = 0; f < 4; ++f) {
            int ao = (arow0 + f * 16 + frl) * 32 + sw;
            ah[f] = *(const bf16x8*)&As_h[ao];
            al[f] = *(const bf16x8*)&As_l[ao];
        }
#pragma unroll
        for (int j = 0; j < 4; ++j) {
            int bo = (bcol0 + j * 16 + frl) * 32 + sw;
            bf16x8 bh = *(const bf16x8*)&Bs_h[bo];
            bf16x8 bl = *(const bf16x8*)&Bs_l[bo];
#pragma unroll
            for (int i = 0; i < 4; ++i) {
                ac[i][j] = __builtin_amdgcn_mfma_f32_16x16x32_bf16(ah[i], bh, ac[i][j], 0, 0, 0);
                ac[i][j] = __builtin_amdgcn_mfma_f32_16x16x32_bf16(ah[i], bl, ac[i][j], 0, 0, 0);
                ac[i][j] = __builtin_amdgcn_mfma_f32_16x16x32_bf16(al[i], bh, ac[i][j], 0, 0, 0);
            }
        }
        __syncthreads();
    };

    if constexpr (EPI == 4) {
#pragma unroll 1
        for (int p = 0; p < 9; ++p) {
            f32x4 acc2[4][4] = {};
#pragma unroll 1
            for (int ks = 0; ks < 8; ++ks) kstep(acc2, p * 256 + ks * 32);
#pragma unroll
            for (int i = 0; i < 4; ++i)
#pragma unroll
                for (int reg = 0; reg < 4; ++reg) {
                    float w = rwv[(long)(r0 + arow0 + i * 16 + kh * 4 + reg) * 9 + p];
#pragma unroll
                    for (int j = 0; j < 4; ++j) acc[i][j][reg] += w * acc2[i][j][reg];
                }
        }
    } else {
#pragma unroll 1
        for (int k0 = 0; k0 < K; k0 += 32) kstep(acc, k0);
    }

#pragma unroll
    for (int i = 0; i < 4; ++i)
#pragma unroll
        for (int reg = 0; reg < 4; ++reg) {
            const int r = r0 + arow0 + i * 16 + kh * 4 + reg;
#pragma unroll
            for (int j = 0; j < 4; ++j) {
                const int c = c0 + bcol0 + j * 16 + frl;
                float v = acc[i][j][reg];
                if constexpr (EPI == 0) {
                    Cf[(long)r * ldc + c] = v + bias[c];
                } else if constexpr (EPI == 1) {
                    Cf[(long)r * ldc + c] = tanhf(v + Cinit[(long)r * ldc + c]);
                } else if constexpr (EPI == 2) {
                    long o = (long)r * ldc + c;
                    v += bf2f(CIh[o]) + bf2f(CIl[o]) + bias[c];
                    u16 h, l; split2(v, h, l); Coh[o] = h; Col[o] = l;
                } else if constexpr (EPI == 3) {
                    long o = (long)r * ldc + c;
                    v = (v + bias[c]) * rwv[(long)r * 9 + (c >> 8)];
                    u16 h, l; split2(v, h, l); Coh[o] = h; Col[o] = l;
                } else if constexpr (EPI == 4) {
#pragma unroll
                    for (int p = 0; p < 9; ++p) v += rwv2[(long)r * 9 + p] * bbrv[p * 1024 + c];
                    Cf[(long)r * ldc + c] = v;
                } else {            // EPI 5
#pragma unroll
                    for (int p = 0; p < 9; ++p) v += rwv[(long)r * 9 + p] * bbrv[p * 1024 + c];
                    Cf[(long)r * ldc + c] = v;
                }
            }
        }
}

// ---------------- logits + softmax / hard ----------------
// hard==0: rwA <- softmax.  hard==1: rwA <- onehot/rwS (ratio), rwH <- onehot.
__global__ void logits_k(const float* __restrict__ h, const float* __restrict__ W2r,
                         const float* __restrict__ b2r, const float* __restrict__ gum,
                         float* __restrict__ rwA, float* __restrict__ rwH,
                         const float* __restrict__ rwS, int hard)
{
    __shared__ float hs[Mm];
    __shared__ float lg[16];
    int n = blockIdx.x;
    for (int i = threadIdx.x; i < Mm; i += 64) hs[i] = h[(long)n * Mm + i];
    __syncthreads();
    if (threadIdx.x < Pp) {
        int p = threadIdx.x;
        float acc = b2r[p];
        for (int m = 0; m < Mm; ++m) acc += hs[m] * W2r[m * Pp + p];
        lg[p] = acc + gum[(long)n * Pp + p];
    }
    __syncthreads();
    if (threadIdx.x == 0) {
        float mx = lg[0]; int am = 0;
#pragma unroll
        for (int p = 1; p < Pp; ++p) if (lg[p] > mx) { mx = lg[p]; am = p; }
        if (hard) {
#pragma unroll
            for (int p = 0; p < Pp; ++p) {
                rwA[(long)n * Pp + p] = (p == am) ? 1.f / rwS[(long)n * Pp + p] : 0.f;
                rwH[(long)n * Pp + p] = (p == am) ? 1.f : 0.f;
            }
        } else {
            float e[Pp]; float ssum = 0.f;
#pragma unroll
            for (int p = 0; p < Pp; ++p) { e[p] = expf(lg[p] - mx); ssum += e[p]; }
#pragma unroll
            for (int p = 0; p < Pp; ++p) rwA[(long)n * Pp + p] = e[p] / ssum;
        }
    }
}

// ---------------- mod-phase RMS norm (group = d % 7) ----------------
template<int INSPLIT, int OUTSPLIT>
__global__ void norm_k(const float* __restrict__ in,
                       const u16* __restrict__ inh, const u16* __restrict__ inl,
                       const float* __restrict__ add, const float* __restrict__ g,
                       float* __restrict__ outf, u16* __restrict__ oh, u16* __restrict__ ol)
{
    __shared__ float sb[256][8];
    __shared__ float dn[8];
    int n = blockIdx.x;
    int t = threadIdx.x;
    float v[4];
#pragma unroll
    for (int j = 0; j < 7; ++j) sb[t][j] = 0.f;
#pragma unroll
    for (int i = 0; i < 4; ++i) {
        int d = t + i * 256;
        long o = (long)n * Dd + d;
        float xv = INSPLIT ? (bf2f(inh[o]) + bf2f(inl[o])) : in[o];
        if (add) xv += add[o];
        v[i] = xv;
        sb[t][d % 7] += xv * xv;
    }
    __syncthreads();
    for (int st = 128; st >= 1; st >>= 1) {
        if (t < st) {
#pragma unroll
            for (int j = 0; j < 7; ++j) sb[t][j] += sb[t + st][j];
        }
        __syncthreads();
    }
    if (t < 7) {
        const float cnt = (t < 2) ? 147.f : 146.f;
        dn[t] = 1.f / sqrtf(sb[0][t] / cnt + EPSf);
    }
    __syncthreads();
#pragma unroll
    for (int i = 0; i < 4; ++i) {
        int d = t + i * 256;
        long o = (long)n * Dd + d;
        float ov = v[i] * dn[d % 7] * g[d];
        if (OUTSPLIT) { u16 h, l; split2(ov, h, l); oh[o] = h; ol[o] = l; }
        else outf[o] = ov;
    }
}

static inline int cdiv(long a, long b) { return (int)((a + b - 1) / b); }

extern "C" void kernel_launch(void* const* d_in, const int* in_sizes, int n_in,
                              void* d_out, int out_size, void* d_ws, size_t ws_size,
                              hipStream_t stream)
{
    const float* x    = (const float*)d_in[0];
    const float* gum  = (const float*)d_in[1];
    const float* mw   = (const float*)d_in[2];
    const float* W1   = (const float*)d_in[3];
    const float* b1   = (const float*)d_in[4];
    const float* th1  = (const float*)d_in[5];
    const float* W2   = (const float*)d_in[6];
    const float* b2   = (const float*)d_in[7];
    const float* th2  = (const float*)d_in[8];
    const float* Wa   = (const float*)d_in[9];
    const float* ba   = (const float*)d_in[10];
    const float* tha  = (const float*)d_in[11];
    const float* Wb   = (const float*)d_in[12];
    const float* bbv  = (const float*)d_in[13];
    const float* thb  = (const float*)d_in[14];
    const float* tW   = (const float*)d_in[15];
    const float* tb   = (const float*)d_in[16];
    const float* tth  = (const float*)d_in[17];
    const float* gnorm = (const float*)d_in[18];

    char* cur = (char*)d_ws;
    auto alloc = [&](size_t bytes) -> void* {
        void* r = (void*)cur; cur += (bytes + 255) & ~(size_t)255; return r;
    };
    void* region = alloc((size_t)Nn * Dd * 4);   // craw f32 == {tinh|tinl} == hbuf f32
    float* craw = (float*)region;
    float* hbuf = (float*)region;
    u16*   tinh = (u16*)region;
    u16*   tinl = tinh + (size_t)Nn * Dd;
    float* zx   = (float*)alloc((size_t)Nn * Mm * 4);
    float* rwS  = (float*)alloc((size_t)Nn * Pp * 4);
    float* rwD  = (float*)alloc((size_t)Nn * Pp * 4);
    float* rwH  = (float*)alloc((size_t)Nn * Pp * 4);
    u16* xmh  = (u16*)alloc((size_t)Nn * Dd * 2);
    u16* xml  = (u16*)alloc((size_t)Nn * Dd * 2);
    u16* colh = (u16*)alloc((size_t)Nn * Dd * 2);
    u16* coll = (u16*)alloc((size_t)Nn * Dd * 2);
    u16* hph  = (u16*)alloc((size_t)Nn * Kc * 2);
    u16* hpl  = (u16*)alloc((size_t)Nn * Kc * 2);
    u16* W1th = (u16*)alloc(256 * 2048 * 2);
    u16* W1tl = (u16*)alloc(256 * 2048 * 2);
    u16* tWth = (u16*)alloc(1024 * 1024 * 2);
    u16* tWtl = (u16*)alloc(1024 * 1024 * 2);
    u16* Wath = (u16*)alloc((size_t)Kc * 1024 * 2);
    u16* Watl = (u16*)alloc((size_t)Kc * 1024 * 2);
    u16* Wbth = (u16*)alloc((size_t)1024 * Kc * 2);
    u16* Wbtl = (u16*)alloc((size_t)1024 * Kc * 2);
    float* W2r = (float*)alloc(256 * 9 * 4);
    float* b1r = (float*)alloc(256 * 4);
    float* b2r = (float*)alloc(16 * 4);
    float* bac = (float*)alloc(Kc * 4);
    float* bbr = (float*)alloc(Pp * 1024 * 4);
    float* tbr = (float*)alloc(1024 * 4);
    if ((size_t)(cur - (char*)d_ws) > ws_size) return;

    float* out0 = (float*)d_out;
    float* out1 = out0 + (long)Nn * Dd;

    // ---- prep ----
    splitW1_k<<<2048, 256, 0, stream>>>(W1, th1, W1th, W1tl);
    splitTW_k<<<4096, 256, 0, stream>>>(tW, tth, tWth, tWtl);
    splitWa_k<<<cdiv((long)Kc * 1024, 256), 256, 0, stream>>>(Wa, tha, Wath, Watl);
    splitWb_k<<<cdiv((long)1024 * Kc, 256), 256, 0, stream>>>(Wb, thb, Wbth, Wbtl);
    rotcopy_k<<<cdiv(256L * 9, 256), 256, 0, stream>>>(W2, W2r, 256, 9, th2, 1);
    rotcopy_k<<<1, 256, 0, stream>>>(b1, b1r, 1, 256, th1, 1);
    rotcopy_k<<<1, 256, 0, stream>>>(b2, b2r, 1, 9, th2, 1);
    rotcopy_k<<<cdiv((long)Pp * Mm, 256), 256, 0, stream>>>(ba, bac, 1, 256, tha, 9);
    rotcopy_k<<<cdiv((long)Pp * 1024, 256), 256, 0, stream>>>(bbv, bbr, 1, 1024, thb, 9);
    rotcopy_k<<<cdiv(1024L, 256), 256, 0, stream>>>(tb, tbr, 1, 1024, tth, 1);

    // ---- x_mixed (split) ----
    mixer_k<<<Nn * Dd / 4 / 256, 256, 0, stream>>>(x, mw, xmh, xml);

    // ---- zx = x_mixed @ W1_top + b1r ----
    mgemm<0><<<dim3(2, 64), 256, 0, stream>>>(
        xmh, xml, 1024, W1th, W1tl, 2048, 1024,
        zx, nullptr, nullptr, 256, nullptr, nullptr, nullptr, b1r, nullptr, nullptr, nullptr);

    for (int t = 0; t < 3; ++t) {
        if (t == 0) {
            tanh_k<<<cdiv((long)Nn * Mm, 256), 256, 0, stream>>>(zx, hbuf, Nn * Mm);
        } else {
            mgemm<1><<<dim3(2, 64), 256, 0, stream>>>(
                colh, coll, 1024, W1th + 1024, W1tl + 1024, 2048, 1024,
                hbuf, nullptr, nullptr, 256, zx, nullptr, nullptr, nullptr, nullptr, nullptr, nullptr);
        }
        logits_k<<<Nn, 64, 0, stream>>>(hbuf, W2r, b2r, gum + (long)t * Nn * Pp,
                                        rwS, nullptr, nullptr, 0);
        if (t == 0) {
            addb_split_k<<<Nn * Dd / 4 / 256, 256, 0, stream>>>(xmh, xml, tbr, tinh, tinl);
        } else {
            mgemm<2><<<dim3(8, 64), 256, 0, stream>>>(
                colh, coll, 1024, tWth, tWtl, 1024, 1024,
                nullptr, tinh, tinl, 1024, nullptr, xmh, xml, tbr, nullptr, nullptr, nullptr);
        }
        // stage A: hp = (tin @ Wat + bac) * rw   (rw folded into epilogue)
        mgemm<3><<<dim3(18, 64), 256, 0, stream>>>(
            tinh, tinl, 1024, Wath, Watl, 1024, 1024,
            nullptr, hph, hpl, Kc, nullptr, nullptr, nullptr, bac, rwS, nullptr, nullptr);
        // stage B: craw = hp @ Wbt + sum_p rw_p bbr_p   (plain K=2304 GEMM)
        mgemm<5><<<dim3(8, 64), 256, 0, stream>>>(
            hph, hpl, Kc, Wbth, Wbtl, Kc, Kc,
            craw, nullptr, nullptr, 1024, nullptr, nullptr, nullptr, nullptr, rwS, nullptr, bbr);
        // collapsed = mod_phase_norm(craw) -> split
        norm_k<0, 1><<<Nn, 256, 0, stream>>>(craw, nullptr, nullptr, nullptr, gnorm,
                                             nullptr, colh, coll);
    }

    // ---- final hard routing (rwS still holds t=2 soft weights) ----
    mgemm<1><<<dim3(2, 64), 256, 0, stream>>>(
        colh, coll, 1024, W1th + 1024, W1tl + 1024, 2048, 1024,
        hbuf, nullptr, nullptr, 256, zx, nullptr, nullptr, nullptr, nullptr, nullptr, nullptr);
    logits_k<<<Nn, 64, 0, stream>>>(hbuf, W2r, b2r, gum + 3L * Nn * Pp,
                                    rwD, rwH, rwS, 1);
    // fc_raw = sum_p (rw_hard/rw_soft2)_p (hp_p @ Wbt_p) + sum_p rw_hard_p bbr_p
    mgemm<4><<<dim3(8, 64), 256, 0, stream>>>(
        hph, hpl, Kc, Wbth, Wbtl, Kc, Kc,
        craw, nullptr, nullptr, 1024, nullptr, nullptr, nullptr, nullptr, rwD, rwH, bbr);
    // out0 = norm(x + fc_raw); out1 = norm(collapsed)
    norm_k<0, 0><<<Nn, 256, 0, stream>>>(craw, nullptr, nullptr, x, gnorm, out0, nullptr, nullptr);
    norm_k<1, 0><<<Nn, 256, 0, stream>>>(nullptr, colh, coll, nullptr, gnorm, out1, nullptr, nullptr);
}

// Round 5
// 1433.803 us; speedup vs baseline: 3.3601x; 1.0102x over previous
//
#include <hip/hip_runtime.h>
#include <hip/hip_bf16.h>

// MobiusCollapseLayer: B=4,S=2048,D=1024,P=9,M=256, 3 twists. N=8192 tokens.
// Round 5: mgemm -> double-buffered LDS, prefetch-next-K-tile, counted vmcnt(8)
// across raw s_barrier (T3/T4 minimum pipeline). Everything else unchanged.
typedef unsigned short u16;
typedef short bf16x8 __attribute__((ext_vector_type(8)));
typedef float f32x4 __attribute__((ext_vector_type(4)));

constexpr int Dd = 1024, Pp = 9, Mm = 256, Nn = 8192, Kc = 2304;
constexpr float EPSf = 1e-6f;

__device__ __forceinline__ float bf2f(u16 u) {
    union { unsigned int u; float f; } v; v.u = ((unsigned int)u) << 16; return v.f;
}
__device__ __forceinline__ u16 f2bf(float f) {
    union { float f; unsigned int u; } v; v.f = f;
    unsigned int r = (v.u + 0x7FFFu + ((v.u >> 16) & 1u)) >> 16; return (u16)r;
}
__device__ __forceinline__ void split2(float v, u16& h, u16& l) {
    h = f2bf(v); l = f2bf(v - bf2f(h));
}
__device__ __forceinline__ void gld16(u16* lds, const u16* g) {
    __builtin_amdgcn_global_load_lds(
        (const __attribute__((address_space(1))) unsigned int*)g,
        (__attribute__((address_space(3))) unsigned int*)lds, 16, 0, 0);
}

// ---------------- weight prep: rotate + transpose + split ----------------
__global__ void rotcopy_k(const float* __restrict__ src, float* __restrict__ dst,
                          int R, int C, const float* __restrict__ theta, int Pb)
{
    long total = (long)Pb * R * C;
    long idx = (long)blockIdx.x * 256 + threadIdx.x;
    if (idx >= total) return;
    int c = (int)(idx % C);
    long rp = idx / C;
    int r = (int)(rp % R);
    int pb = (int)(rp / R);
    float th = theta[pb];
    const float* s = src + ((long)pb * R + r) * C;
    float v;
    if (c == 0)      v = s[0] * cosf(th) - s[1] * sinf(th);
    else if (c == 1) v = s[0] * sinf(th) + s[1] * cosf(th);
    else             v = s[c];
    dst[idx] = v;
}

__global__ void splitW1_k(const float* __restrict__ W1, const float* __restrict__ th,
                          u16* __restrict__ h, u16* __restrict__ l)
{
    int idx = blockIdx.x * 256 + threadIdx.x;
    if (idx >= 256 * 2048) return;
    int k = idx & 2047, n = idx >> 11;
    float v;
    if (n == 0)      v = W1[(long)k * 256 + 0] * cosf(th[0]) - W1[(long)k * 256 + 1] * sinf(th[0]);
    else if (n == 1) v = W1[(long)k * 256 + 0] * sinf(th[0]) + W1[(long)k * 256 + 1] * cosf(th[0]);
    else             v = W1[(long)k * 256 + n];
    u16 hh, ll; split2(v, hh, ll); h[idx] = hh; l[idx] = ll;
}

__global__ void splitTW_k(const float* __restrict__ tW, const float* __restrict__ th,
                          u16* __restrict__ h, u16* __restrict__ l)
{
    int idx = blockIdx.x * 256 + threadIdx.x;
    if (idx >= 1024 * 1024) return;
    int k = idx & 1023, n = idx >> 10;
    float v;
    if (n == 0)      v = tW[(long)k * 1024 + 0] * cosf(th[0]) - tW[(long)k * 1024 + 1] * sinf(th[0]);
    else if (n == 1) v = tW[(long)k * 1024 + 0] * sinf(th[0]) + tW[(long)k * 1024 + 1] * cosf(th[0]);
    else             v = tW[(long)k * 1024 + n];
    u16 hh, ll; split2(v, hh, ll); h[idx] = hh; l[idx] = ll;
}

__global__ void splitWa_k(const float* __restrict__ Wa, const float* __restrict__ tha,
                          u16* __restrict__ h, u16* __restrict__ l)
{
    int idx = blockIdx.x * 256 + threadIdx.x;
    if (idx >= Kc * 1024) return;
    int k = idx & 1023, n = idx >> 10;
    int p = n >> 8, m = n & 255;
    const float* s = Wa + ((long)p * 1024 + k) * 256;
    float v;
    if (m == 0)      v = s[0] * cosf(tha[p]) - s[1] * sinf(tha[p]);
    else if (m == 1) v = s[0] * sinf(tha[p]) + s[1] * cosf(tha[p]);
    else             v = s[m];
    u16 hh, ll; split2(v, hh, ll); h[idx] = hh; l[idx] = ll;
}

__global__ void splitWb_k(const float* __restrict__ Wb, const float* __restrict__ thb,
                          u16* __restrict__ h, u16* __restrict__ l)
{
    int idx = blockIdx.x * 256 + threadIdx.x;
    if (idx >= 1024 * Kc) return;
    int n = idx / Kc;              // d
    int k = idx - n * Kc;          // p*256+m
    int p = k >> 8, m = k & 255;
    const float* s = Wb + ((long)p * 256 + m) * 1024;
    float v;
    if (n == 0)      v = s[0] * cosf(thb[p]) - s[1] * sinf(thb[p]);
    else if (n == 1) v = s[0] * sinf(thb[p]) + s[1] * cosf(thb[p]);
    else             v = s[n];
    u16 hh, ll; split2(v, hh, ll); h[idx] = hh; l[idx] = ll;
}

// ---------------- neighbor mixer -> split bf16 ----------------
__global__ void mixer_k(const float* __restrict__ x, const float* __restrict__ mw,
                        u16* __restrict__ xmh, u16* __restrict__ xml)
{
    int idx = blockIdx.x * 256 + threadIdx.x;       // float4 index, total N*D/4
    if (idx >= Nn * Dd / 4) return;
    int d4 = idx & (Dd / 4 - 1);
    int n = idx >> 8;
    int s = n & 2047;                               // S=2048
    const float4* x4 = (const float4*)x;
    const float4* w4 = (const float4*)mw;
    float4 xc = x4[idx];
    float4 w0 = w4[d4], w1 = w4[(Dd / 4) + d4], w2 = w4[2 * (Dd / 4) + d4];
    float o[4];
    o[0] = xc.x * w0.x; o[1] = xc.y * w0.y; o[2] = xc.z * w0.z; o[3] = xc.w * w0.w;
    if (s > 0) {
        float4 xl = x4[idx - Dd / 4];
        o[0] += xl.x * w1.x; o[1] += xl.y * w1.y; o[2] += xl.z * w1.z; o[3] += xl.w * w1.w;
    }
    if (s < 2047) {
        float4 xr = x4[idx + Dd / 4];
        o[0] += xr.x * w2.x; o[1] += xr.y * w2.y; o[2] += xr.z * w2.z; o[3] += xr.w * w2.w;
    }
    ushort4 h4, l4;
    split2(o[0], h4.x, l4.x); split2(o[1], h4.y, l4.y);
    split2(o[2], h4.z, l4.z); split2(o[3], h4.w, l4.w);
    ((ushort4*)xmh)[idx] = h4; ((ushort4*)xml)[idx] = l4;
}

__global__ void tanh_k(const float* __restrict__ a, float* __restrict__ o, int total)
{
    int idx = blockIdx.x * 256 + threadIdx.x;
    if (idx < total) o[idx] = tanhf(a[idx]);
}

__global__ void addb_split_k(const u16* __restrict__ xmh, const u16* __restrict__ xml,
                             const float* __restrict__ tbr,
                             u16* __restrict__ th_, u16* __restrict__ tl_)
{
    int idx = blockIdx.x * 256 + threadIdx.x;   // ushort4 index over N*D/4
    if (idx >= Nn * Dd / 4) return;
    int d4 = idx & (Dd / 4 - 1);
    ushort4 xh = ((const ushort4*)xmh)[idx], xl = ((const ushort4*)xml)[idx];
    float4 b = ((const float4*)tbr)[d4];
    ushort4 h4, l4;
    split2(bf2f(xh.x) + bf2f(xl.x) + b.x, h4.x, l4.x);
    split2(bf2f(xh.y) + bf2f(xl.y) + b.y, h4.y, l4.y);
    split2(bf2f(xh.z) + bf2f(xl.z) + b.z, h4.z, l4.z);
    split2(bf2f(xh.w) + bf2f(xl.w) + b.w, h4.w, l4.w);
    ((ushort4*)th_)[idx] = h4; ((ushort4*)tl_)[idx] = l4;
}

// ---------------- split-bf16 MFMA GEMM: C = A x B^T(stored [n][k]) ----------------
// 128x128 tile, BK=32, 4 waves (64x64), 4x4 frags 16x16x32, 3-term split.
// Double-buffered LDS + prefetch + counted vmcnt(8) across raw s_barrier.
// EPI 0: +bias -> f32                       (zx)
// EPI 1: tanh(acc + Cinit) -> f32           (obs)
// EPI 2: acc + CIsplit + bias -> split out  (twist)
// EPI 3: (acc + bias) * rw[r][c>>8] -> split out  (stage A, rw-folded)
// EPI 4: per-256K-block scale by rwv (=rw_hard/rw_soft2); + sum_p rwv2*bbr (final)
// EPI 5: acc + sum_p rwv*bbr -> f32         (stage B twists, plain K=2304)
template<int EPI>
__global__ __launch_bounds__(256, 2) void mgemm(
    const u16* __restrict__ Agh, const u16* __restrict__ Agl, int lda,
    const u16* __restrict__ Bgh, const u16* __restrict__ Bgl, int ldb,
    int K,
    float* __restrict__ Cf, u16* __restrict__ Coh, u16* __restrict__ Col, int ldc,
    const float* __restrict__ Cinit,
    const u16* __restrict__ CIh, const u16* __restrict__ CIl,
    const float* __restrict__ bias,
    const float* __restrict__ rwv,
    const float* __restrict__ rwv2,
    const float* __restrict__ bbrv)
{
    __shared__ u16 smem[2][16384];              // per buf: Ah|Al|Bh|Bl, each 128x32
    const int tid = threadIdx.x, wave = tid >> 6, lane = tid & 63;
    // T1: XCD-aware swizzle (all grids are multiples of 8 blocks)
    const int nwg = gridDim.x * gridDim.y;
    const int flat = blockIdx.y * gridDim.x + blockIdx.x;
    const int q = nwg >> 3;
    const int l_ = (flat & 7) * q + (flat >> 3);
    const int r0 = (l_ / gridDim.x) * 128, c0 = (l_ % gridDim.x) * 128;
    // staging lane constants (pre-swizzled global source; linear LDS dest)
    const int srl = lane >> 2;
    const int ssl = ((lane & 3) ^ ((lane >> 3) & 3)) * 8;
    // fragment read constants (swizzled ds_read: slot = k16 ^ ((row>>1)&3))
    const int frl = lane & 15, kh = lane >> 4;
    const int sw  = (kh ^ ((frl >> 1) & 3)) * 8;
    const int arow0 = (wave >> 1) * 64, bcol0 = (wave & 1) * 64;
    const int w32 = wave * 32;

    f32x4 acc[4][4] = {};
    f32x4 acc2[4][4];
    if constexpr (EPI == 4) {
#pragma unroll
        for (int i = 0; i < 4; ++i)
#pragma unroll
            for (int j = 0; j < 4; ++j) acc2[i][j] = f32x4{0.f, 0.f, 0.f, 0.f};
    }

    auto STAGE = [&](int buf, int k0) {
        u16* base = &smem[buf][0];
        u16* As_h = base;        u16* As_l = base + 4096;
        u16* Bs_h = base + 8192; u16* Bs_l = base + 12288;
        const long ga0 = (long)(r0 + w32 + srl) * lda + k0 + ssl;
        gld16(&As_h[w32 * 32],        Agh + ga0);
        gld16(&As_h[(w32 + 16) * 32], Agh + ga0 + 16L * lda);
        gld16(&As_l[w32 * 32],        Agl + ga0);
        gld16(&As_l[(w32 + 16) * 32], Agl + ga0 + 16L * lda);
        const long gb0 = (long)(c0 + w32 + srl) * ldb + k0 + ssl;
        gld16(&Bs_h[w32 * 32],        Bgh + gb0);
        gld16(&Bs_h[(w32 + 16) * 32], Bgh + gb0 + 16L * ldb);
        gld16(&Bs_l[w32 * 32],        Bgl + gb0);
        gld16(&Bs_l[(w32 + 16) * 32], Bgl + gb0 + 16L * ldb);
    };
    auto COMPUTE = [&](int buf, f32x4 (&ac)[4][4]) {
        u16* base = &smem[buf][0];
        u16* As_h = base;        u16* As_l = base + 4096;
        u16* Bs_h = base + 8192; u16* Bs_l = base + 12288;
        bf16x8 ah[4], al[4];
#pragma unroll
        for (int f = 0; f < 4; ++f) {
            int ao = (arow0 + f * 16 + frl) * 32 + sw;
            ah[f] = *(const bf16x8*)&As_h[ao];
            al[f] = *(const bf16x8*)&As_l[ao];
        }
#pragma unroll
        for (int j = 0; j < 4; ++j) {
            int bo = (bcol0 + j * 16 + frl) * 32 + sw;
            bf16x8 bh = *(const bf16x8*)&Bs_h[bo];
            bf16x8 bl = *(const bf16x8*)&Bs_l[bo];
#pragma unroll
            for (int i = 0; i < 4; ++i) {
                ac[i][j] = __builtin_amdgcn_mfma_f32_16x16x32_bf16(ah[i], bh, ac[i][j], 0, 0, 0);
                ac[i][j] = __builtin_amdgcn_mfma_f32_16x16x32_bf16(ah[i], bl, ac[i][j], 0, 0, 0);
                ac[i][j] = __builtin_amdgcn_mfma_f32_16x16x32_bf16(al[i], bh, ac[i][j], 0, 0, 0);
            }
        }
    };
    auto FLUSH = [&](int p) {       // EPI4: acc += rw[r][p] * acc2; acc2 = 0
#pragma unroll
        for (int i = 0; i < 4; ++i)
#pragma unroll
            for (int reg = 0; reg < 4; ++reg) {
                float w = rwv[(long)(r0 + arow0 + i * 16 + kh * 4 + reg) * 9 + p];
#pragma unroll
                for (int j = 0; j < 4; ++j) {
                    acc[i][j][reg] += w * acc2[i][j][reg];
                    acc2[i][j][reg] = 0.f;
                }
            }
    };

    const int NT = K / 32;          // always even here (32 / 64 / 72)
    STAGE(0, 0);
#pragma unroll 1
    for (int t = 0; t < NT; t += 2) {
        // ---- even step: compute buf0, prefetch into buf1 ----
        STAGE(1, (t + 1) * 32);
        asm volatile("s_waitcnt vmcnt(8)" ::: "memory");
        __builtin_amdgcn_sched_barrier(0);
        __builtin_amdgcn_s_barrier();
        __builtin_amdgcn_sched_barrier(0);
        if constexpr (EPI == 4) COMPUTE(0, acc2); else COMPUTE(0, acc);
        __builtin_amdgcn_sched_barrier(0);
        __builtin_amdgcn_s_barrier();
        __builtin_amdgcn_sched_barrier(0);
        // ---- odd step: compute buf1, prefetch into buf0 ----
        if (t + 2 < NT) {
            STAGE(0, (t + 2) * 32);
            asm volatile("s_waitcnt vmcnt(8)" ::: "memory");
        } else {
            asm volatile("s_waitcnt vmcnt(0)" ::: "memory");
        }
        __builtin_amdgcn_sched_barrier(0);
        __builtin_amdgcn_s_barrier();
        __builtin_amdgcn_sched_barrier(0);
        if constexpr (EPI == 4) COMPUTE(1, acc2); else COMPUTE(1, acc);
        __builtin_amdgcn_sched_barrier(0);
        __builtin_amdgcn_s_barrier();
        __builtin_amdgcn_sched_barrier(0);
        if constexpr (EPI == 4) {
            if (((t + 1) & 7) == 7) FLUSH((t + 1) >> 3);
        }
    }

#pragma unroll
    for (int i = 0; i < 4; ++i)
#pragma unroll
        for (int reg = 0; reg < 4; ++reg) {
            const int r = r0 + arow0 + i * 16 + kh * 4 + reg;
#pragma unroll
            for (int j = 0; j < 4; ++j) {
                const int c = c0 + bcol0 + j * 16 + frl;
                float v = acc[i][j][reg];
                if constexpr (EPI == 0) {
                    Cf[(long)r * ldc + c] = v + bias[c];
                } else if constexpr (EPI == 1) {
                    Cf[(long)r * ldc + c] = tanhf(v + Cinit[(long)r * ldc + c]);
                } else if constexpr (EPI == 2) {
                    long o = (long)r * ldc + c;
                    v += bf2f(CIh[o]) + bf2f(CIl[o]) + bias[c];
                    u16 h, l; split2(v, h, l); Coh[o] = h; Col[o] = l;
                } else if constexpr (EPI == 3) {
                    long o = (long)r * ldc + c;
                    v = (v + bias[c]) * rwv[(long)r * 9 + (c >> 8)];
                    u16 h, l; split2(v, h, l); Coh[o] = h; Col[o] = l;
                } else if constexpr (EPI == 4) {
#pragma unroll
                    for (int p = 0; p < 9; ++p) v += rwv2[(long)r * 9 + p] * bbrv[p * 1024 + c];
                    Cf[(long)r * ldc + c] = v;
                } else {            // EPI 5
#pragma unroll
                    for (int p = 0; p < 9; ++p) v += rwv[(long)r * 9 + p] * bbrv[p * 1024 + c];
                    Cf[(long)r * ldc + c] = v;
                }
            }
        }
}

// ---------------- logits + softmax / hard ----------------
// hard==0: rwA <- softmax.  hard==1: rwA <- onehot/rwS (ratio), rwH <- onehot.
__global__ void logits_k(const float* __restrict__ h, const float* __restrict__ W2r,
                         const float* __restrict__ b2r, const float* __restrict__ gum,
                         float* __restrict__ rwA, float* __restrict__ rwH,
                         const float* __restrict__ rwS, int hard)
{
    __shared__ float hs[Mm];
    __shared__ float lg[16];
    int n = blockIdx.x;
    for (int i = threadIdx.x; i < Mm; i += 64) hs[i] = h[(long)n * Mm + i];
    __syncthreads();
    if (threadIdx.x < Pp) {
        int p = threadIdx.x;
        float acc = b2r[p];
        for (int m = 0; m < Mm; ++m) acc += hs[m] * W2r[m * Pp + p];
        lg[p] = acc + gum[(long)n * Pp + p];
    }
    __syncthreads();
    if (threadIdx.x == 0) {
        float mx = lg[0]; int am = 0;
#pragma unroll
        for (int p = 1; p < Pp; ++p) if (lg[p] > mx) { mx = lg[p]; am = p; }
        if (hard) {
#pragma unroll
            for (int p = 0; p < Pp; ++p) {
                rwA[(long)n * Pp + p] = (p == am) ? 1.f / rwS[(long)n * Pp + p] : 0.f;
                rwH[(long)n * Pp + p] = (p == am) ? 1.f : 0.f;
            }
        } else {
            float e[Pp]; float ssum = 0.f;
#pragma unroll
            for (int p = 0; p < Pp; ++p) { e[p] = expf(lg[p] - mx); ssum += e[p]; }
#pragma unroll
            for (int p = 0; p < Pp; ++p) rwA[(long)n * Pp + p] = e[p] / ssum;
        }
    }
}

// ---------------- mod-phase RMS norm (group = d % 7) ----------------
template<int INSPLIT, int OUTSPLIT>
__global__ void norm_k(const float* __restrict__ in,
                       const u16* __restrict__ inh, const u16* __restrict__ inl,
                       const float* __restrict__ add, const float* __restrict__ g,
                       float* __restrict__ outf, u16* __restrict__ oh, u16* __restrict__ ol)
{
    __shared__ float sb[256][8];
    __shared__ float dn[8];
    int n = blockIdx.x;
    int t = threadIdx.x;
    float v[4];
#pragma unroll
    for (int j = 0; j < 7; ++j) sb[t][j] = 0.f;
#pragma unroll
    for (int i = 0; i < 4; ++i) {
        int d = t + i * 256;
        long o = (long)n * Dd + d;
        float xv = INSPLIT ? (bf2f(inh[o]) + bf2f(inl[o])) : in[o];
        if (add) xv += add[o];
        v[i] = xv;
        sb[t][d % 7] += xv * xv;
    }
    __syncthreads();
    for (int st = 128; st >= 1; st >>= 1) {
        if (t < st) {
#pragma unroll
            for (int j = 0; j < 7; ++j) sb[t][j] += sb[t + st][j];
        }
        __syncthreads();
    }
    if (t < 7) {
        const float cnt = (t < 2) ? 147.f : 146.f;
        dn[t] = 1.f / sqrtf(sb[0][t] / cnt + EPSf);
    }
    __syncthreads();
#pragma unroll
    for (int i = 0; i < 4; ++i) {
        int d = t + i * 256;
        long o = (long)n * Dd + d;
        float ov = v[i] * dn[d % 7] * g[d];
        if (OUTSPLIT) { u16 h, l; split2(ov, h, l); oh[o] = h; ol[o] = l; }
        else outf[o] = ov;
    }
}

static inline int cdiv(long a, long b) { return (int)((a + b - 1) / b); }

extern "C" void kernel_launch(void* const* d_in, const int* in_sizes, int n_in,
                              void* d_out, int out_size, void* d_ws, size_t ws_size,
                              hipStream_t stream)
{
    const float* x    = (const float*)d_in[0];
    const float* gum  = (const float*)d_in[1];
    const float* mw   = (const float*)d_in[2];
    const float* W1   = (const float*)d_in[3];
    const float* b1   = (const float*)d_in[4];
    const float* th1  = (const float*)d_in[5];
    const float* W2   = (const float*)d_in[6];
    const float* b2   = (const float*)d_in[7];
    const float* th2  = (const float*)d_in[8];
    const float* Wa   = (const float*)d_in[9];
    const float* ba   = (const float*)d_in[10];
    const float* tha  = (const float*)d_in[11];
    const float* Wb   = (const float*)d_in[12];
    const float* bbv  = (const float*)d_in[13];
    const float* thb  = (const float*)d_in[14];
    const float* tW   = (const float*)d_in[15];
    const float* tb   = (const float*)d_in[16];
    const float* tth  = (const float*)d_in[17];
    const float* gnorm = (const float*)d_in[18];

    char* cur = (char*)d_ws;
    auto alloc = [&](size_t bytes) -> void* {
        void* r = (void*)cur; cur += (bytes + 255) & ~(size_t)255; return r;
    };
    void* region = alloc((size_t)Nn * Dd * 4);   // craw f32 == {tinh|tinl} == hbuf f32
    float* craw = (float*)region;
    float* hbuf = (float*)region;
    u16*   tinh = (u16*)region;
    u16*   tinl = tinh + (size_t)Nn * Dd;
    float* zx   = (float*)alloc((size_t)Nn * Mm * 4);
    float* rwS  = (float*)alloc((size_t)Nn * Pp * 4);
    float* rwD  = (float*)alloc((size_t)Nn * Pp * 4);
    float* rwH  = (float*)alloc((size_t)Nn * Pp * 4);
    u16* xmh  = (u16*)alloc((size_t)Nn * Dd * 2);
    u16* xml  = (u16*)alloc((size_t)Nn * Dd * 2);
    u16* colh = (u16*)alloc((size_t)Nn * Dd * 2);
    u16* coll = (u16*)alloc((size_t)Nn * Dd * 2);
    u16* hph  = (u16*)alloc((size_t)Nn * Kc * 2);
    u16* hpl  = (u16*)alloc((size_t)Nn * Kc * 2);
    u16* W1th = (u16*)alloc(256 * 2048 * 2);
    u16* W1tl = (u16*)alloc(256 * 2048 * 2);
    u16* tWth = (u16*)alloc(1024 * 1024 * 2);
    u16* tWtl = (u16*)alloc(1024 * 1024 * 2);
    u16* Wath = (u16*)alloc((size_t)Kc * 1024 * 2);
    u16* Watl = (u16*)alloc((size_t)Kc * 1024 * 2);
    u16* Wbth = (u16*)alloc((size_t)1024 * Kc * 2);
    u16* Wbtl = (u16*)alloc((size_t)1024 * Kc * 2);
    float* W2r = (float*)alloc(256 * 9 * 4);
    float* b1r = (float*)alloc(256 * 4);
    float* b2r = (float*)alloc(16 * 4);
    float* bac = (float*)alloc(Kc * 4);
    float* bbr = (float*)alloc(Pp * 1024 * 4);
    float* tbr = (float*)alloc(1024 * 4);
    if ((size_t)(cur - (char*)d_ws) > ws_size) return;

    float* out0 = (float*)d_out;
    float* out1 = out0 + (long)Nn * Dd;

    // ---- prep ----
    splitW1_k<<<2048, 256, 0, stream>>>(W1, th1, W1th, W1tl);
    splitTW_k<<<4096, 256, 0, stream>>>(tW, tth, tWth, tWtl);
    splitWa_k<<<cdiv((long)Kc * 1024, 256), 256, 0, stream>>>(Wa, tha, Wath, Watl);
    splitWb_k<<<cdiv((long)1024 * Kc, 256), 256, 0, stream>>>(Wb, thb, Wbth, Wbtl);
    rotcopy_k<<<cdiv(256L * 9, 256), 256, 0, stream>>>(W2, W2r, 256, 9, th2, 1);
    rotcopy_k<<<1, 256, 0, stream>>>(b1, b1r, 1, 256, th1, 1);
    rotcopy_k<<<1, 256, 0, stream>>>(b2, b2r, 1, 9, th2, 1);
    rotcopy_k<<<cdiv((long)Pp * Mm, 256), 256, 0, stream>>>(ba, bac, 1, 256, tha, 9);
    rotcopy_k<<<cdiv((long)Pp * 1024, 256), 256, 0, stream>>>(bbv, bbr, 1, 1024, thb, 9);
    rotcopy_k<<<cdiv(1024L, 256), 256, 0, stream>>>(tb, tbr, 1, 1024, tth, 1);

    // ---- x_mixed (split) ----
    mixer_k<<<Nn * Dd / 4 / 256, 256, 0, stream>>>(x, mw, xmh, xml);

    // ---- zx = x_mixed @ W1_top + b1r ----
    mgemm<0><<<dim3(2, 64), 256, 0, stream>>>(
        xmh, xml, 1024, W1th, W1tl, 2048, 1024,
        zx, nullptr, nullptr, 256, nullptr, nullptr, nullptr, b1r, nullptr, nullptr, nullptr);

    for (int t = 0; t < 3; ++t) {
        if (t == 0) {
            tanh_k<<<cdiv((long)Nn * Mm, 256), 256, 0, stream>>>(zx, hbuf, Nn * Mm);
        } else {
            mgemm<1><<<dim3(2, 64), 256, 0, stream>>>(
                colh, coll, 1024, W1th + 1024, W1tl + 1024, 2048, 1024,
                hbuf, nullptr, nullptr, 256, zx, nullptr, nullptr, nullptr, nullptr, nullptr, nullptr);
        }
        logits_k<<<Nn, 64, 0, stream>>>(hbuf, W2r, b2r, gum + (long)t * Nn * Pp,
                                        rwS, nullptr, nullptr, 0);
        if (t == 0) {
            addb_split_k<<<Nn * Dd / 4 / 256, 256, 0, stream>>>(xmh, xml, tbr, tinh, tinl);
        } else {
            mgemm<2><<<dim3(8, 64), 256, 0, stream>>>(
                colh, coll, 1024, tWth, tWtl, 1024, 1024,
                nullptr, tinh, tinl, 1024, nullptr, xmh, xml, tbr, nullptr, nullptr, nullptr);
        }
        // stage A: hp = (tin @ Wat + bac) * rw   (rw folded into epilogue)
        mgemm<3><<<dim3(18, 64), 256, 0, stream>>>(
            tinh, tinl, 1024, Wath, Watl, 1024, 1024,
            nullptr, hph, hpl, Kc, nullptr, nullptr, nullptr, bac, rwS, nullptr, nullptr);
        // stage B: craw = hp @ Wbt + sum_p rw_p bbr_p   (plain K=2304 GEMM)
        mgemm<5><<<dim3(8, 64), 256, 0, stream>>>(
            hph, hpl, Kc, Wbth, Wbtl, Kc, Kc,
            craw, nullptr, nullptr, 1024, nullptr, nullptr, nullptr, nullptr, rwS, nullptr, bbr);
        // collapsed = mod_phase_norm(craw) -> split
        norm_k<0, 1><<<Nn, 256, 0, stream>>>(craw, nullptr, nullptr, nullptr, gnorm,
                                             nullptr, colh, coll);
    }

    // ---- final hard routing (rwS still holds t=2 soft weights) ----
    mgemm<1><<<dim3(2, 64), 256, 0, stream>>>(
        colh, coll, 1024, W1th + 1024, W1tl + 1024, 2048, 1024,
        hbuf, nullptr, nullptr, 256, zx, nullptr, nullptr, nullptr, nullptr, nullptr, nullptr);
    logits_k<<<Nn, 64, 0, stream>>>(hbuf, W2r, b2r, gum + 3L * Nn * Pp,
                                    rwD, rwH, rwS, 1);
    // fc_raw = sum_p (rw_hard/rw_soft2)_p (hp_p @ Wbt_p) + sum_p rw_hard_p bbr_p
    mgemm<4><<<dim3(8, 64), 256, 0, stream>>>(
        hph, hpl, Kc, Wbth, Wbtl, Kc, Kc,
        craw, nullptr, nullptr, 1024, nullptr, nullptr, nullptr, nullptr, rwD, rwH, bbr);
    // out0 = norm(x + fc_raw); out1 = norm(collapsed)
    norm_k<0, 0><<<Nn, 256, 0, stream>>>(craw, nullptr, nullptr, x, gnorm, out0, nullptr, nullptr);
    norm_k<1, 0><<<Nn, 256, 0, stream>>>(nullptr, colh, coll, nullptr, gnorm, out1, nullptr, nullptr);
}